// Round 3
// baseline (476.363 us; speedup 1.0000x reference)
//
#include <hip/hip_runtime.h>
#include <math.h>

typedef __attribute__((ext_vector_type(8))) short short8;
typedef __attribute__((ext_vector_type(4))) float f32x4;
typedef unsigned short u16;
typedef unsigned int u32;

#define HW   96
#define LPIX 9216
static constexpr float kScale = 0.17677669529663687f;  // 1/sqrt(32)

__device__ inline u16 f2bf(float f) {
    u32 x = __float_as_uint(f);
    return (u16)((x + 0x7fffu + ((x >> 16) & 1u)) >> 16);   // RNE
}
__device__ inline float bf2f(u16 v) { return __uint_as_float((u32)v << 16); }

// global -> LDS direct copy, 16B per lane. LDS dest is wave-uniform base +
// lane*16 (HW semantics); global src is per-lane.
typedef __attribute__((address_space(1))) const void gas_t;
typedef __attribute__((address_space(3))) void las_t;
__device__ __forceinline__ void g2lds16(const void* g, void* l) {
    __builtin_amdgcn_global_load_lds((gas_t*)g, (las_t*)l, 16, 0, 0);
}

// ---------------------------------------------------------------------------
// NCHW fp32 -> NHWC bf16 transpose-cast. grid (96 y, 8 b), block 256.
// ---------------------------------------------------------------------------
template <int C>
__global__ __launch_bounds__(256) void cast_nchw_nhwc(
    const float* __restrict__ in, u16* __restrict__ out)
{
    const int y = blockIdx.x, b = blockIdx.y, tid = threadIdx.x;
    __shared__ float sT[HW * C];
    for (int i = tid; i < HW * C; i += 256) {
        int c = i / HW, xx = i - c * HW;
        sT[xx * C + c] = in[(((size_t)b * C + c) * HW + y) * HW + xx];
    }
    __syncthreads();
    for (int i = tid; i < HW * (C / 8); i += 256) {
        int c8 = i % (C / 8), xx = i / (C / 8);
        union { short8 v8; u16 u[8]; } pk;
#pragma unroll
        for (int j = 0; j < 8; ++j) pk.u[j] = f2bf(sT[xx * C + c8 * 8 + j]);
        *(short8*)&out[(((size_t)b * HW + y) * HW + xx) * C + c8 * 8] = pk.v8;
    }
}

// ---------------------------------------------------------------------------
// conv weights [co 128][ci CIN][3][3] fp32 -> swizzled granule layout for
// direct global_load_lds staging (see conv_gemm).
// ---------------------------------------------------------------------------
__global__ void cast_conv_w(const float* __restrict__ w, u16* __restrict__ wp, int CIN)
{
    int n = 9 * CIN * 128;
    int i = blockIdx.x * 256 + threadIdx.x;
    if (i >= n) return;
    int NC = CIN >> 5;
    int e  = i & 7;
    int gr = i >> 3;                 // granule index
    int cc = gr / 2304;              // (coh*NC + c)
    int gi = gr - cc * 2304;
    int coh = cc / NC, c = cc - coh * NC;
    int f = gi >> 8;
    int m = (gi >> 2) & 63;
    int s = gi & 3;
    int qq = (s - (m >> 1)) & 3;
    int co = coh * 64 + m;
    int ci = c * 32 + qq * 8 + e;
    wp[i] = f2bf(w[(size_t)(co * CIN + ci) * 9 + f]);
}

// ---------------------------------------------------------------------------
// attn weights [324][128] fp32 -> pre-swizzled granule layout for direct
// global_load_lds staging in attn_mfma:
//   wp[h][c4 4][rr 96][s 4][e 8], ci = c4*32 + ((s-(rr>>1))&3)*8 + e,
//   rows 81..95 zero-padded. 4*1536 granules total.
// ---------------------------------------------------------------------------
__global__ void cast_attn_w(const float* __restrict__ aw, u16* __restrict__ wp)
{
    int i = blockIdx.x * 256 + threadIdx.x;
    if (i >= 4 * 1536 * 8) return;
    int e = i & 7;
    int g = i >> 3;
    int h = g / 1536, r = g - h * 1536;
    int c4 = r / 384, r2 = r - c4 * 384;
    int rr = r2 >> 2, s = r2 & 3;
    int qq = (s - (rr >> 1)) & 3;
    int ci = c4 * 32 + qq * 8 + e;
    float v = (rr < 81) ? aw[(size_t)(h * 81 + rr) * 128 + ci] : 0.f;
    wp[i] = f2bf(v);
}

// dense matrix fp32 -> bf16 (same layout)
__global__ void cast_mat(const float* __restrict__ in, u16* __restrict__ out, int n)
{
    int i = blockIdx.x * 256 + threadIdx.x;
    if (i < n) out[i] = f2bf(in[i]);
}

// ---------------------------------------------------------------------------
// conv3x3 + BN + ReLU, v3: weights-in-LDS, global_load_lds everything.
// (unchanged from R2 — see comments there)
// ---------------------------------------------------------------------------
template <int CIN, bool OUT_F32>
__global__ __launch_bounds__(192, 2) void conv_gemm(
    const u16* __restrict__ in, const u16* __restrict__ wp,
    const float* __restrict__ g, const float* __restrict__ be, void* outv)
{
    constexpr int NC    = CIN / 32;      // 32-ci chunks (2 or 4)
    constexpr int WBYT  = 36864;         // weight region bytes (2304 granules)
    constexpr int NHG   = 1928;          // halo granules (482 rows x 4)

    const int bx  = blockIdx.x;          // 0..63
    const int b   = blockIdx.y;
    const int coh = bx >> 5;
    const int gg  = bx & 31;
    const int gsw = (gg & 7) * 4 + (gg >> 3);   // row-group swizzle (same-XCD neighbors)
    const int y0  = gsw * 3;             // rows y0..y0+2
    const int l0h = y0 * 96 - 97;        // halo flat-pixel origin

    const int tid = threadIdx.x, lane = tid & 63, wv = tid >> 6;  // wv = row
    const int lx = lane & 15, q = lane >> 4;

    __shared__ __align__(16) char smem[WBYT + NHG * 16];   // 67,712 B
    float* sT = (float*)smem;            // epilogue [144 px][65] f32 (37,440 B)

    // precomputed per-lane pieces
    const int aoff = lx * 64 + (((q + (lx >> 1)) & 3) << 4);   // af addr (weights)
    const int pb   = wv * 96 + lx;                             // bfr pixel-row base

    f32x4 acc[4][6];
#pragma unroll
    for (int mt = 0; mt < 4; ++mt)
#pragma unroll
        for (int nt = 0; nt < 6; ++nt) acc[mt][nt] = (f32x4){0.f, 0.f, 0.f, 0.f};

    const u16* inb = in + (size_t)b * LPIX * CIN;

#pragma unroll
    for (int c = 0; c < NC; ++c) {
        if (c) __syncthreads();          // previous chunk's readers done

        // ---- stage weights: 2304 granules, linear LDS, pre-swizzled source ----
        {
            const u16* wqb = wp + ((size_t)(coh * NC + c)) * 2304 * 8;
#pragma unroll
            for (int j = 0; j < 12; ++j) {
                int gj = j * 192 + tid;
                g2lds16(&wqb[(size_t)gj * 8],
                        (char*)smem + (j * 192 + wv * 64) * 16);
            }
        }
        // ---- stage halo: 1928 granules, clamped rows, swizzled source q ----
#pragma unroll
        for (int i = 0; i < 11; ++i) {
            int gi = i * 192 + tid;
            if (gi < NHG) {
                int p = gi >> 2, s = gi & 3;
                int qq = (s - (p >> 1)) & 3;
                int lh = l0h + p;
                lh = lh < 0 ? 0 : (lh >= LPIX ? LPIX - 1 : lh);
                g2lds16(&inb[(size_t)lh * CIN + c * 32 + qq * 8],
                        (char*)smem + WBYT + (i * 192 + wv * 64) * 16);
            }
        }
        asm volatile("s_waitcnt vmcnt(0)" ::: "memory");
        __builtin_amdgcn_s_barrier();
        asm volatile("" ::: "memory");

        // ---- compute: 9 taps x 24 MFMA, all operands from LDS ----
#pragma unroll
        for (int f = 0; f < 9; ++f) {
            const int dy = f / 3 - 1, dx = f % 3 - 1;
            const int off = dy * 96 + dx + 97;           // [0,194]
            const bool vy = (unsigned)(y0 + wv + dy) < 96u;
            short8 af[4], bfr[6];
#pragma unroll
            for (int mt = 0; mt < 4; ++mt)
                af[mt] = *(const short8*)((const char*)smem + f * 4096 + mt * 1024 + aoff);
#pragma unroll
            for (int nt = 0; nt < 6; ++nt) {
                int p = pb + nt * 16 + off;
                int slot = (q + (p >> 1)) & 3;
                short8 t8 = *(const short8*)((const char*)smem + WBYT + p * 64 + slot * 16);
                bool ok = vy & ((unsigned)(nt * 16 + lx + dx) < 96u);
                bfr[nt] = ok ? t8 : (short8){0, 0, 0, 0, 0, 0, 0, 0};
            }
#pragma unroll
            for (int mt = 0; mt < 4; ++mt)
#pragma unroll
                for (int nt = 0; nt < 6; ++nt)
                    acc[mt][nt] = __builtin_amdgcn_mfma_f32_16x16x32_bf16(
                        af[mt], bfr[nt], acc[mt][nt], 0, 0, 0);
        }
    }

    const float rs = rsqrtf(1.f + 1e-5f);
    if (OUT_F32) {
        float* out = (float*)outv;
#pragma unroll
        for (int mt = 0; mt < 4; ++mt) {
#pragma unroll
            for (int reg = 0; reg < 4; ++reg) {
                int co = coh * 64 + mt * 16 + q * 4 + reg;
                float sc = g[co] * rs, bb = be[co];
#pragma unroll
                for (int nt = 0; nt < 6; ++nt) {
                    int l = (y0 + wv) * 96 + nt * 16 + lx;
                    out[((size_t)b * 128 + co) * LPIX + l] =
                        fmaxf(fmaf(acc[mt][nt][reg], sc, bb), 0.f);
                }
            }
        }
    } else {
        u16* out = (u16*)outv;
#pragma unroll
        for (int hh = 0; hh < 2; ++hh) {               // two 48-px halves
            __syncthreads();
#pragma unroll
            for (int mt = 0; mt < 4; ++mt)
#pragma unroll
                for (int nn = 0; nn < 3; ++nn) {
                    int nt = hh * 3 + nn;
#pragma unroll
                    for (int reg = 0; reg < 4; ++reg)
                        sT[(wv * 48 + nn * 16 + lx) * 65 + mt * 16 + q * 4 + reg] =
                            acc[mt][nt][reg];
                }
            __syncthreads();
            for (int i = tid; i < 1152; i += 192) {
                int cog = i & 7, pxl = i >> 3;
                int wrr = pxl / 48, ofs = pxl - wrr * 48;
                int l = (y0 + wrr) * 96 + hh * 48 + ofs;
                union { short8 v8; u16 u[8]; } pk;
#pragma unroll
                for (int j = 0; j < 8; ++j) {
                    int co = coh * 64 + cog * 8 + j;
                    pk.u[j] = f2bf(fmaxf(fmaf(sT[pxl * 65 + cog * 8 + j], g[co] * rs, be[co]), 0.f));
                }
                *(short8*)&out[((size_t)b * LPIX + l) * 128 + coh * 64 + cog * 8] = pk.v8;
            }
        }
    }
}

// ---------------------------------------------------------------------------
// 128->128 linear + bias via MFMA. in/out NHWC-flat bf16 [b*L][128].
// grid 1152 (64 px per block), block 256 (2x2 waves: M=64 x N=32).
// ---------------------------------------------------------------------------
__global__ __launch_bounds__(256) void linear_mfma(
    const u16* __restrict__ in, const u16* __restrict__ wp,
    const float* __restrict__ bias, u16* __restrict__ out)
{
    const int l0 = blockIdx.x * 64;
    const int tid = threadIdx.x, lane = tid & 63, wv = tid >> 6;
    const int wm = wv >> 1, wn = wv & 1;
    const int lx = lane & 15, q = lane >> 4;

    __shared__ char smem[4 * 64 * 40 * 2 + 4 * 128 * 40 * 2];   // 61,440 B
    u16* sX = (u16*)smem;                        // [c4][px 64][32 pitch 40]
    u16* sW = (u16*)(smem + 4 * 64 * 40 * 2);    // [c4][co 128][32 pitch 40]
    float* sT = (float*)smem;                    // epilogue [64][65]

    for (int i = tid; i < 1024; i += 256) {
        int k8 = i & 15, px = i >> 4;
        short8 v = *(const short8*)&in[((size_t)(l0 + px)) * 128 + k8 * 8];
        *(short8*)&sX[((k8 >> 2) * 64 + px) * 40 + (k8 & 3) * 8] = v;
    }
    for (int i = tid; i < 2048; i += 256) {
        int k8 = i & 15, co = i >> 4;
        short8 v = *(const short8*)&wp[(size_t)co * 128 + k8 * 8];
        *(short8*)&sW[((k8 >> 2) * 128 + co) * 40 + (k8 & 3) * 8] = v;
    }
    __syncthreads();

    f32x4 acc[4][2];
#pragma unroll
    for (int mt = 0; mt < 4; ++mt)
#pragma unroll
        for (int nt = 0; nt < 2; ++nt) acc[mt][nt] = (f32x4){0.f, 0.f, 0.f, 0.f};

#pragma unroll
    for (int c4 = 0; c4 < 4; ++c4) {
        short8 af[4], bfr[2];
#pragma unroll
        for (int mt = 0; mt < 4; ++mt)
            af[mt] = *(const short8*)&sW[(c4 * 128 + wm * 64 + mt * 16 + lx) * 40 + q * 8];
#pragma unroll
        for (int nt = 0; nt < 2; ++nt)
            bfr[nt] = *(const short8*)&sX[(c4 * 64 + wn * 32 + nt * 16 + lx) * 40 + q * 8];
#pragma unroll
        for (int mt = 0; mt < 4; ++mt)
#pragma unroll
            for (int nt = 0; nt < 2; ++nt)
                acc[mt][nt] = __builtin_amdgcn_mfma_f32_16x16x32_bf16(
                    af[mt], bfr[nt], acc[mt][nt], 0, 0, 0);
    }

    for (int mh = 0; mh < 2; ++mh) {
        __syncthreads();
        if (wm == mh) {
#pragma unroll
            for (int mt = 0; mt < 4; ++mt)
#pragma unroll
                for (int nt = 0; nt < 2; ++nt)
#pragma unroll
                    for (int reg = 0; reg < 4; ++reg)
                        sT[(wn * 32 + nt * 16 + lx) * 65 + mt * 16 + q * 4 + reg] =
                            acc[mt][nt][reg];
        }
        __syncthreads();
        for (int i = tid; i < 512; i += 256) {
            int cog = i & 7, px = i >> 3;
            union { short8 v8; u16 u[8]; } pk;
#pragma unroll
            for (int j = 0; j < 8; ++j) {
                int co = mh * 64 + cog * 8 + j;
                pk.u[j] = f2bf(sT[px * 65 + cog * 8 + j] + bias[co]);
            }
            *(short8*)&out[((size_t)(l0 + px)) * 128 + mh * 64 + cog * 8] = pk.v8;
        }
    }
}

// ---------------------------------------------------------------------------
// attn logits GEMM (MFMA) + bias + scale + softmax over q(9), v2:
//  * 128 px per block: grid (72, 4, 8) = 2304 blocks, block 256 (4 waves,
//    each 32 px x 96 rows: acc[2][6], 48 MFMA/wave between barriers).
//  * sX (32,768 B) and sW (24,576 B) staged via global_load_lds(16B) with
//    granule-slot swizzle (q+(row>>1))&3 -> 2-way ds_read_b128 (free).
//    sW source is pre-swizzled (cast_attn_w), so its stage is linear bulk.
//  * LDS 57,344 B -> 2 blocks/CU. Epilogue sL [128][97] f32 reuses smem.
// ---------------------------------------------------------------------------
__global__ __launch_bounds__(256, 2) void attn_mfma(
    const u16* __restrict__ fgb, const u16* __restrict__ awp,
    const float* __restrict__ ab, u16* __restrict__ A)
{
    const int lt = blockIdx.x, h = blockIdx.y, b = blockIdx.z;
    const int l0 = lt * 128;
    const int tid = threadIdx.x, lane = tid & 63, wv = tid >> 6;
    const int lx = lane & 15, q = lane >> 4;

    __shared__ __align__(16) char smem[57344];
    float* sL = (float*)smem;            // epilogue logits [128][97] (49,664 B)

    // ---- stage sX: [c4 4][px 128][4 slots][16B] = 2048 granules ----
    const u16* fb = fgb + ((size_t)b * LPIX + l0) * 128;
#pragma unroll
    for (int i = 0; i < 8; ++i) {
        int gg = i * 256 + tid;
        int c4 = gg >> 9, r = gg & 511, px = r >> 2, s = r & 3;
        int qq = (s - (px >> 1)) & 3;
        g2lds16(&fb[(size_t)px * 128 + c4 * 32 + qq * 8],
                (char*)smem + (i * 256 + wv * 64) * 16);
    }
    // ---- stage sW: 1536 granules, pre-swizzled linear source ----
    const u16* wb = awp + (size_t)h * 1536 * 8;
#pragma unroll
    for (int i = 0; i < 6; ++i) {
        g2lds16(&wb[(size_t)(i * 256 + tid) * 8],
                (char*)smem + 32768 + (i * 256 + wv * 64) * 16);
    }
    asm volatile("s_waitcnt vmcnt(0)" ::: "memory");
    __builtin_amdgcn_s_barrier();
    asm volatile("" ::: "memory");

    f32x4 acc[2][6];
#pragma unroll
    for (int nt = 0; nt < 2; ++nt)
#pragma unroll
        for (int j = 0; j < 6; ++j) acc[nt][j] = (f32x4){0.f, 0.f, 0.f, 0.f};

#pragma unroll
    for (int c4 = 0; c4 < 4; ++c4) {
        short8 af[2], bfr[6];
#pragma unroll
        for (int nt = 0; nt < 2; ++nt) {
            int px = wv * 32 + nt * 16 + lx;
            af[nt] = *(const short8*)((const char*)smem + c4 * 8192 + px * 64
                                      + (((q + (px >> 1)) & 3) << 4));
        }
#pragma unroll
        for (int j = 0; j < 6; ++j) {
            int rr = j * 16 + lx;
            bfr[j] = *(const short8*)((const char*)smem + 32768 + c4 * 6144 + rr * 64
                                      + (((q + (rr >> 1)) & 3) << 4));
        }
#pragma unroll
        for (int nt = 0; nt < 2; ++nt)
#pragma unroll
            for (int j = 0; j < 6; ++j)
                acc[nt][j] = __builtin_amdgcn_mfma_f32_16x16x32_bf16(
                    af[nt], bfr[j], acc[nt][j], 0, 0, 0);
    }

    __syncthreads();   // done reading sX/sW; reuse as sL
#pragma unroll
    for (int nt = 0; nt < 2; ++nt)
#pragma unroll
        for (int j = 0; j < 6; ++j)
#pragma unroll
            for (int reg = 0; reg < 4; ++reg)
                sL[(wv * 32 + nt * 16 + q * 4 + reg) * 97 + j * 16 + lx] =
                    acc[nt][j][reg];
    __syncthreads();

    for (int t = tid; t < 1152; t += 256) {
        int px = t & 127, p = t >> 7;
        const int rbase = h * 81 + p * 9;
        float lg[9], m = -1e30f;
#pragma unroll
        for (int qq = 0; qq < 9; ++qq) {
            lg[qq] = (sL[px * 97 + p * 9 + qq] + ab[rbase + qq]) * kScale;
            m = fmaxf(m, lg[qq]);
        }
        float s = 0.f;
#pragma unroll
        for (int qq = 0; qq < 9; ++qq) { lg[qq] = __expf(lg[qq] - m); s += lg[qq]; }
        float inv = 1.f / s;
        u16* Ab = &A[(((size_t)(b * 4 + h) * 9 + p) * 9) * LPIX + l0 + px];
#pragma unroll
        for (int qq = 0; qq < 9; ++qq) Ab[(size_t)qq * LPIX] = f2bf(lg[qq] * inv);
    }
}

// ---------------------------------------------------------------------------
// fused einsum + fold (5x5 stencil collapse).
// Block 384 = one head x 4 full rows (384 px). Coalesced A reads (lane=px),
// v staged per-head in LDS (rows y0-2..y0+5 x 96 x 32ch bf16 = 49,152 B).
// grid (24 y-tiles, 4 h, 8 b).
// ---------------------------------------------------------------------------
__global__ __launch_bounds__(384, 4) void attn_fold(
    const u16* __restrict__ A, const u16* __restrict__ v,
    u16* __restrict__ out)
{
    const int yt = blockIdx.x, h = blockIdx.y, b = blockIdx.z;
    const int y0 = yt * 4;
    const int tid = threadIdx.x;          // 0..383
    const int yl  = tid / 96;             // 0..3
    const int x   = tid - yl * 96;
    const int y   = y0 + yl;
    const int l   = y * 96 + x;

    __shared__ u16 sV[8 * 96 * 32];       // [r 8][xx 96][c 32] bf16 = 49,152 B

    // ---- stage v rows y0-2 .. y0+5 (this head's 32 ch) ----
    const u16* vb = v + (size_t)b * LPIX * 128 + h * 32;
    for (int t = tid; t < 3072; t += 384) {
        int k = t & 3, s = t >> 2;        // s = r*96+xx, k = uint4 within 64B
        int r = s / 96, xx = s - r * 96;
        int gy = y0 - 2 + r;
        uint4 uu = make_uint4(0u, 0u, 0u, 0u);
        if ((unsigned)gy < 96u)
            uu = *(const uint4*)&vb[(size_t)(gy * 96 + xx) * 128 + k * 8];
        *(uint4*)&sV[(size_t)s * 32 + k * 8] = uu;
    }

    // ---- stencil S[5][5] from 9 taps x 9 q of A (coalesced bf16 reads) ----
    float S[25];
#pragma unroll
    for (int i = 0; i < 25; ++i) S[i] = 0.f;

    const u16* Ab = A + ((size_t)(b * 4 + h) * 81) * (size_t)LPIX;
#pragma unroll
    for (int ki = 0; ki < 3; ++ki) {
        const int ly = y + 1 - ki;
        const bool vy = ((unsigned)ly < 96u);
#pragma unroll
        for (int kj = 0; kj < 3; ++kj) {
            const int lx2 = x + 1 - kj;
            if (vy && (unsigned)lx2 < 96u) {
                const u16* Ap = Ab + (size_t)(ki * 3 + kj) * 9 * (size_t)LPIX
                              + (ly * 96 + lx2);
#pragma unroll
                for (int qq = 0; qq < 9; ++qq) {
                    const int qi = qq / 3, qj = qq - qi * 3;
                    S[(qi - ki + 2) * 5 + (qj - kj + 2)] += bf2f(Ap[(size_t)qq * LPIX]);
                }
            }
        }
    }

    __syncthreads();   // staging complete before LDS reads

    // ---- 5x5 stencil over LDS v tile ----
    float acc[32];
#pragma unroll
    for (int c = 0; c < 32; ++c) acc[c] = 0.f;

#pragma unroll
    for (int oy = 0; oy < 5; ++oy) {
        const int r = yl + oy;            // LDS row: gy = y0-2+r = y+oy-2
#pragma unroll
        for (int ox = 0; ox < 5; ++ox) {
            const int xx = x + ox - 2;
            if ((unsigned)xx >= 96u) continue;
            const float sc = S[oy * 5 + ox];
            const u16* vp = &sV[(size_t)(r * 96 + xx) * 32];
#pragma unroll
            for (int c8 = 0; c8 < 4; ++c8) {
                const uint4 uu = *(const uint4*)&vp[c8 * 8];
                acc[c8 * 8 + 0] = fmaf(sc, __uint_as_float(uu.x << 16),          acc[c8 * 8 + 0]);
                acc[c8 * 8 + 1] = fmaf(sc, __uint_as_float(uu.x & 0xffff0000u), acc[c8 * 8 + 1]);
                acc[c8 * 8 + 2] = fmaf(sc, __uint_as_float(uu.y << 16),          acc[c8 * 8 + 2]);
                acc[c8 * 8 + 3] = fmaf(sc, __uint_as_float(uu.y & 0xffff0000u), acc[c8 * 8 + 3]);
                acc[c8 * 8 + 4] = fmaf(sc, __uint_as_float(uu.z << 16),          acc[c8 * 8 + 4]);
                acc[c8 * 8 + 5] = fmaf(sc, __uint_as_float(uu.z & 0xffff0000u), acc[c8 * 8 + 5]);
                acc[c8 * 8 + 6] = fmaf(sc, __uint_as_float(uu.w << 16),          acc[c8 * 8 + 6]);
                acc[c8 * 8 + 7] = fmaf(sc, __uint_as_float(uu.w & 0xffff0000u), acc[c8 * 8 + 7]);
            }
        }
    }

    u16* ob = &out[((size_t)b * LPIX + l) * 128 + h * 32];
#pragma unroll
    for (int gidx = 0; gidx < 4; ++gidx) {
        union { short8 v8; u16 u[8]; } pk;
#pragma unroll
        for (int j = 0; j < 8; ++j) pk.u[j] = f2bf(acc[gidx * 8 + j]);
        *(short8*)&ob[gidx * 8] = pk.v8;
    }
}

// ---------------------------------------------------------------------------
extern "C" void kernel_launch(void* const* d_in, const int* in_sizes, int n_in,
                              void* d_out, int out_size, void* d_ws, size_t ws_size,
                              hipStream_t stream)
{
    const float* x    = (const float*)d_in[0];
    const float* fg   = (const float*)d_in[1];
    const float* c1w  = (const float*)d_in[2];
    const float* bn1g = (const float*)d_in[3];
    const float* bn1b = (const float*)d_in[4];
    const float* c2w  = (const float*)d_in[5];
    const float* bn2g = (const float*)d_in[6];
    const float* bn2b = (const float*)d_in[7];
    const float* vw   = (const float*)d_in[8];
    const float* vb   = (const float*)d_in[9];
    const float* aw   = (const float*)d_in[10];
    const float* abv  = (const float*)d_in[11];
    const float* pw   = (const float*)d_in[12];
    const float* pb   = (const float*)d_in[13];
    const float* c3w  = (const float*)d_in[14];
    const float* bn3g = (const float*)d_in[15];
    const float* bn3b = (const float*)d_in[16];
    const float* c4w  = (const float*)d_in[17];
    const float* bn4g = (const float*)d_in[18];
    const float* bn4b = (const float*)d_in[19];

    char* wsp = (char*)d_ws;
    size_t off = 0;
    auto carve = [&](size_t bytes) {
        void* pp = wsp + off;
        off += (bytes + 255) & ~(size_t)255;
        return pp;
    };
    u16*   xb   = (u16*)carve((size_t)8 * LPIX * 64 * 2);     // x NHWC bf16
    u16*   fgb  = (u16*)carve((size_t)8 * LPIX * 128 * 2);    // fg NHWC bf16
    u16*   actA = (u16*)carve((size_t)8 * LPIX * 128 * 2);
    u16*   actB = (u16*)carve((size_t)8 * LPIX * 128 * 2);
    u16*   Abuf = (u16*)carve((size_t)8 * 324 * LPIX * 2);    // A bf16
    u16*   w1p  = (u16*)carve((size_t)9 * 2 * 128 * 32 * 2);
    u16*   w2p  = (u16*)carve((size_t)9 * 4 * 128 * 32 * 2);
    u16*   w3p  = (u16*)carve((size_t)9 * 4 * 128 * 32 * 2);
    u16*   w4p  = (u16*)carve((size_t)9 * 4 * 128 * 32 * 2);
    u16*   vwp  = (u16*)carve((size_t)128 * 128 * 2);
    u16*   pwp  = (u16*)carve((size_t)128 * 128 * 2);
    u16*   awp  = (u16*)carve((size_t)4 * 1536 * 8 * 2);      // pre-swizzled attn W

    // --- pre-casts ---
    cast_nchw_nhwc<64><<<dim3(HW, 8), 256, 0, stream>>>(x, xb);
    cast_nchw_nhwc<128><<<dim3(HW, 8), 256, 0, stream>>>(fg, fgb);
    cast_conv_w<<<(9 * 64 * 128 + 255) / 256, 256, 0, stream>>>(c1w, w1p, 64);
    cast_conv_w<<<(9 * 128 * 128 + 255) / 256, 256, 0, stream>>>(c2w, w2p, 128);
    cast_conv_w<<<(9 * 128 * 128 + 255) / 256, 256, 0, stream>>>(c3w, w3p, 128);
    cast_conv_w<<<(9 * 128 * 128 + 255) / 256, 256, 0, stream>>>(c4w, w4p, 128);
    cast_mat<<<(16384 + 255) / 256, 256, 0, stream>>>(vw, vwp, 16384);
    cast_mat<<<(16384 + 255) / 256, 256, 0, stream>>>(pw, pwp, 16384);
    cast_attn_w<<<192, 256, 0, stream>>>(aw, awp);

    // --- pipeline ---
    conv_gemm<64, false><<<dim3(64, 8), 192, 0, stream>>>(xb, w1p, bn1g, bn1b, actA);
    conv_gemm<128, false><<<dim3(64, 8), 192, 0, stream>>>(actA, w2p, bn2g, bn2b, actB);
    linear_mfma<<<1152, 256, 0, stream>>>(actB, vwp, vb, actA);                 // v
    attn_mfma<<<dim3(72, 4, 8), 256, 0, stream>>>(fgb, awp, abv, Abuf);
    attn_fold<<<dim3(24, 4, 8), 384, 0, stream>>>(Abuf, actA, actB);            // folded
    linear_mfma<<<1152, 256, 0, stream>>>(actB, pwp, pb, actA);                 // p
    conv_gemm<128, false><<<dim3(64, 8), 192, 0, stream>>>(actA, w3p, bn3g, bn3b, actB);
    conv_gemm<128, true><<<dim3(64, 8), 192, 0, stream>>>(actB, w4p, bn4g, bn4b, d_out);
}

// Round 4
// 466.382 us; speedup vs baseline: 1.0214x; 1.0214x over previous
//
#include <hip/hip_runtime.h>
#include <math.h>

typedef __attribute__((ext_vector_type(8))) short short8;
typedef __attribute__((ext_vector_type(4))) float f32x4;
typedef unsigned short u16;
typedef unsigned int u32;

#define HW   96
#define LPIX 9216
static constexpr float kScale = 0.17677669529663687f;  // 1/sqrt(32)

__device__ inline u16 f2bf(float f) {
    u32 x = __float_as_uint(f);
    return (u16)((x + 0x7fffu + ((x >> 16) & 1u)) >> 16);   // RNE
}
__device__ inline float bf2f(u16 v) { return __uint_as_float((u32)v << 16); }

// global -> LDS direct copy, 16B per lane. LDS dest is wave-uniform base +
// lane*16 (HW semantics); global src is per-lane.
typedef __attribute__((address_space(1))) const void gas_t;
typedef __attribute__((address_space(3))) void las_t;
__device__ __forceinline__ void g2lds16(const void* g, void* l) {
    __builtin_amdgcn_global_load_lds((gas_t*)g, (las_t*)l, 16, 0, 0);
}

// ---------------------------------------------------------------------------
// NCHW fp32 -> NHWC bf16 transpose-cast. grid (96 y, 8 b), block 256.
// ---------------------------------------------------------------------------
template <int C>
__global__ __launch_bounds__(256) void cast_nchw_nhwc(
    const float* __restrict__ in, u16* __restrict__ out)
{
    const int y = blockIdx.x, b = blockIdx.y, tid = threadIdx.x;
    __shared__ float sT[HW * C];
    for (int i = tid; i < HW * C; i += 256) {
        int c = i / HW, xx = i - c * HW;
        sT[xx * C + c] = in[(((size_t)b * C + c) * HW + y) * HW + xx];
    }
    __syncthreads();
    for (int i = tid; i < HW * (C / 8); i += 256) {
        int c8 = i % (C / 8), xx = i / (C / 8);
        union { short8 v8; u16 u[8]; } pk;
#pragma unroll
        for (int j = 0; j < 8; ++j) pk.u[j] = f2bf(sT[xx * C + c8 * 8 + j]);
        *(short8*)&out[(((size_t)b * HW + y) * HW + xx) * C + c8 * 8] = pk.v8;
    }
}

// ---------------------------------------------------------------------------
// conv weights [co 128][ci CIN][3][3] fp32 -> swizzled granule layout for
// direct global_load_lds staging (see conv_gemm).
// ---------------------------------------------------------------------------
__global__ void cast_conv_w(const float* __restrict__ w, u16* __restrict__ wp, int CIN)
{
    int n = 9 * CIN * 128;
    int i = blockIdx.x * 256 + threadIdx.x;
    if (i >= n) return;
    int NC = CIN >> 5;
    int e  = i & 7;
    int gr = i >> 3;                 // granule index
    int cc = gr / 2304;              // (coh*NC + c)
    int gi = gr - cc * 2304;
    int coh = cc / NC, c = cc - coh * NC;
    int f = gi >> 8;
    int m = (gi >> 2) & 63;
    int s = gi & 3;
    int qq = (s - (m >> 1)) & 3;
    int co = coh * 64 + m;
    int ci = c * 32 + qq * 8 + e;
    wp[i] = f2bf(w[(size_t)(co * CIN + ci) * 9 + f]);
}

// ---------------------------------------------------------------------------
// attn weights [324][128] fp32 -> pre-swizzled granule layout for direct
// global_load_lds staging in attn_mfma:
//   wp[h][c4 4][rr 96][s 4][e 8], ci = c4*32 + ((s-(rr>>1))&3)*8 + e,
//   rows 81..95 zero-padded. 4*1536 granules total.
// ---------------------------------------------------------------------------
__global__ void cast_attn_w(const float* __restrict__ aw, u16* __restrict__ wp)
{
    int i = blockIdx.x * 256 + threadIdx.x;
    if (i >= 4 * 1536 * 8) return;
    int e = i & 7;
    int g = i >> 3;
    int h = g / 1536, r = g - h * 1536;
    int c4 = r / 384, r2 = r - c4 * 384;
    int rr = r2 >> 2, s = r2 & 3;
    int qq = (s - (rr >> 1)) & 3;
    int ci = c4 * 32 + qq * 8 + e;
    float v = (rr < 81) ? aw[(size_t)(h * 81 + rr) * 128 + ci] : 0.f;
    wp[i] = f2bf(v);
}

// dense matrix fp32 -> bf16 (same layout)
__global__ void cast_mat(const float* __restrict__ in, u16* __restrict__ out, int n)
{
    int i = blockIdx.x * 256 + threadIdx.x;
    if (i < n) out[i] = f2bf(in[i]);
}

// ---------------------------------------------------------------------------
// conv3x3 + BN + ReLU, v3.1: weights-in-LDS, global_load_lds everything.
// Change vs v3: OUT_F32 epilogue now goes through an LDS transpose and
// writes NCHW fp32 as contiguous float4 runs (192B per (co,row,half)),
// instead of 96 scattered 4B stores per lane (store-latency-bound at
// 6 waves/CU: measured 509 GB/s effective, 74us).
// ---------------------------------------------------------------------------
template <int CIN, bool OUT_F32>
__global__ __launch_bounds__(192, 2) void conv_gemm(
    const u16* __restrict__ in, const u16* __restrict__ wp,
    const float* __restrict__ g, const float* __restrict__ be, void* outv)
{
    constexpr int NC    = CIN / 32;      // 32-ci chunks (2 or 4)
    constexpr int WBYT  = 36864;         // weight region bytes (2304 granules)
    constexpr int NHG   = 1928;          // halo granules (482 rows x 4)

    const int bx  = blockIdx.x;          // 0..63
    const int b   = blockIdx.y;
    const int coh = bx >> 5;
    const int gg  = bx & 31;
    const int gsw = (gg & 7) * 4 + (gg >> 3);   // row-group swizzle (same-XCD neighbors)
    const int y0  = gsw * 3;             // rows y0..y0+2
    const int l0h = y0 * 96 - 97;        // halo flat-pixel origin

    const int tid = threadIdx.x, lane = tid & 63, wv = tid >> 6;  // wv = row
    const int lx = lane & 15, q = lane >> 4;

    __shared__ __align__(16) char smem[WBYT + NHG * 16];   // 67,712 B
    float* sT = (float*)smem;            // epilogue (bf16 path) [144 px][65] f32
    float* sF = (float*)smem;            // epilogue (f32 path) [64 co][148] f32 (37,888 B)

    // precomputed per-lane pieces
    const int aoff = lx * 64 + (((q + (lx >> 1)) & 3) << 4);   // af addr (weights)
    const int pb   = wv * 96 + lx;                             // bfr pixel-row base

    f32x4 acc[4][6];
#pragma unroll
    for (int mt = 0; mt < 4; ++mt)
#pragma unroll
        for (int nt = 0; nt < 6; ++nt) acc[mt][nt] = (f32x4){0.f, 0.f, 0.f, 0.f};

    const u16* inb = in + (size_t)b * LPIX * CIN;

#pragma unroll
    for (int c = 0; c < NC; ++c) {
        if (c) __syncthreads();          // previous chunk's readers done

        // ---- stage weights: 2304 granules, linear LDS, pre-swizzled source ----
        {
            const u16* wqb = wp + ((size_t)(coh * NC + c)) * 2304 * 8;
#pragma unroll
            for (int j = 0; j < 12; ++j) {
                int gj = j * 192 + tid;
                g2lds16(&wqb[(size_t)gj * 8],
                        (char*)smem + (j * 192 + wv * 64) * 16);
            }
        }
        // ---- stage halo: 1928 granules, clamped rows, swizzled source q ----
#pragma unroll
        for (int i = 0; i < 11; ++i) {
            int gi = i * 192 + tid;
            if (gi < NHG) {
                int p = gi >> 2, s = gi & 3;
                int qq = (s - (p >> 1)) & 3;
                int lh = l0h + p;
                lh = lh < 0 ? 0 : (lh >= LPIX ? LPIX - 1 : lh);
                g2lds16(&inb[(size_t)lh * CIN + c * 32 + qq * 8],
                        (char*)smem + WBYT + (i * 192 + wv * 64) * 16);
            }
        }
        asm volatile("s_waitcnt vmcnt(0)" ::: "memory");
        __builtin_amdgcn_s_barrier();
        asm volatile("" ::: "memory");

        // ---- compute: 9 taps x 24 MFMA, all operands from LDS ----
#pragma unroll
        for (int f = 0; f < 9; ++f) {
            const int dy = f / 3 - 1, dx = f % 3 - 1;
            const int off = dy * 96 + dx + 97;           // [0,194]
            const bool vy = (unsigned)(y0 + wv + dy) < 96u;
            short8 af[4], bfr[6];
#pragma unroll
            for (int mt = 0; mt < 4; ++mt)
                af[mt] = *(const short8*)((const char*)smem + f * 4096 + mt * 1024 + aoff);
#pragma unroll
            for (int nt = 0; nt < 6; ++nt) {
                int p = pb + nt * 16 + off;
                int slot = (q + (p >> 1)) & 3;
                short8 t8 = *(const short8*)((const char*)smem + WBYT + p * 64 + slot * 16);
                bool ok = vy & ((unsigned)(nt * 16 + lx + dx) < 96u);
                bfr[nt] = ok ? t8 : (short8){0, 0, 0, 0, 0, 0, 0, 0};
            }
#pragma unroll
            for (int mt = 0; mt < 4; ++mt)
#pragma unroll
                for (int nt = 0; nt < 6; ++nt)
                    acc[mt][nt] = __builtin_amdgcn_mfma_f32_16x16x32_bf16(
                        af[mt], bfr[nt], acc[mt][nt], 0, 0, 0);
        }
    }

    const float rs = rsqrtf(1.f + 1e-5f);
    if (OUT_F32) {
        // NCHW fp32 output via LDS transpose -> contiguous float4 stores.
        float* out = (float*)outv;
#pragma unroll
        for (int hh = 0; hh < 2; ++hh) {               // two 48-px halves
            __syncthreads();                           // LDS readers (or prev half) done
#pragma unroll
            for (int mt = 0; mt < 4; ++mt)
#pragma unroll
                for (int nn = 0; nn < 3; ++nn) {
                    int nt = hh * 3 + nn;
#pragma unroll
                    for (int reg = 0; reg < 4; ++reg)
                        sF[(mt * 16 + q * 4 + reg) * 148 + wv * 48 + nn * 16 + lx] =
                            acc[mt][nt][reg];
                }
            __syncthreads();
            // 2304 float4 granules: i = co*36 + wrr*12 + j  (12 granules/row-half)
            for (int i = tid; i < 2304; i += 192) {
                int co = i / 36, r2 = i - co * 36;
                int wrr = r2 / 12, j = r2 - wrr * 12;
                int gco = coh * 64 + co;
                float sc = g[gco] * rs, bb = be[gco];
                const float* sp = &sF[co * 148 + wrr * 48 + j * 4];
                f32x4 vv = *(const f32x4*)sp;          // 16B-aligned (148*4 % 16 == 0)
#pragma unroll
                for (int e = 0; e < 4; ++e) vv[e] = fmaxf(fmaf(vv[e], sc, bb), 0.f);
                *(f32x4*)&out[((size_t)b * 128 + gco) * LPIX
                              + (y0 + wrr) * 96 + hh * 48 + j * 4] = vv;
            }
        }
    } else {
        u16* out = (u16*)outv;
#pragma unroll
        for (int hh = 0; hh < 2; ++hh) {               // two 48-px halves
            __syncthreads();
#pragma unroll
            for (int mt = 0; mt < 4; ++mt)
#pragma unroll
                for (int nn = 0; nn < 3; ++nn) {
                    int nt = hh * 3 + nn;
#pragma unroll
                    for (int reg = 0; reg < 4; ++reg)
                        sT[(wv * 48 + nn * 16 + lx) * 65 + mt * 16 + q * 4 + reg] =
                            acc[mt][nt][reg];
                }
            __syncthreads();
            for (int i = tid; i < 1152; i += 192) {
                int cog = i & 7, pxl = i >> 3;
                int wrr = pxl / 48, ofs = pxl - wrr * 48;
                int l = (y0 + wrr) * 96 + hh * 48 + ofs;
                union { short8 v8; u16 u[8]; } pk;
#pragma unroll
                for (int j = 0; j < 8; ++j) {
                    int co = coh * 64 + cog * 8 + j;
                    pk.u[j] = f2bf(fmaxf(fmaf(sT[pxl * 65 + cog * 8 + j], g[co] * rs, be[co]), 0.f));
                }
                *(short8*)&out[((size_t)b * LPIX + l) * 128 + coh * 64 + cog * 8] = pk.v8;
            }
        }
    }
}

// ---------------------------------------------------------------------------
// 128->128 linear + bias via MFMA. in/out NHWC-flat bf16 [b*L][128].
// grid 1152 (64 px per block), block 256 (2x2 waves: M=64 x N=32).
// ---------------------------------------------------------------------------
__global__ __launch_bounds__(256) void linear_mfma(
    const u16* __restrict__ in, const u16* __restrict__ wp,
    const float* __restrict__ bias, u16* __restrict__ out)
{
    const int l0 = blockIdx.x * 64;
    const int tid = threadIdx.x, lane = tid & 63, wv = tid >> 6;
    const int wm = wv >> 1, wn = wv & 1;
    const int lx = lane & 15, q = lane >> 4;

    __shared__ char smem[4 * 64 * 40 * 2 + 4 * 128 * 40 * 2];   // 61,440 B
    u16* sX = (u16*)smem;                        // [c4][px 64][32 pitch 40]
    u16* sW = (u16*)(smem + 4 * 64 * 40 * 2);    // [c4][co 128][32 pitch 40]
    float* sT = (float*)smem;                    // epilogue [64][65]

    for (int i = tid; i < 1024; i += 256) {
        int k8 = i & 15, px = i >> 4;
        short8 v = *(const short8*)&in[((size_t)(l0 + px)) * 128 + k8 * 8];
        *(short8*)&sX[((k8 >> 2) * 64 + px) * 40 + (k8 & 3) * 8] = v;
    }
    for (int i = tid; i < 2048; i += 256) {
        int k8 = i & 15, co = i >> 4;
        short8 v = *(const short8*)&wp[(size_t)co * 128 + k8 * 8];
        *(short8*)&sW[((k8 >> 2) * 128 + co) * 40 + (k8 & 3) * 8] = v;
    }
    __syncthreads();

    f32x4 acc[4][2];
#pragma unroll
    for (int mt = 0; mt < 4; ++mt)
#pragma unroll
        for (int nt = 0; nt < 2; ++nt) acc[mt][nt] = (f32x4){0.f, 0.f, 0.f, 0.f};

#pragma unroll
    for (int c4 = 0; c4 < 4; ++c4) {
        short8 af[4], bfr[2];
#pragma unroll
        for (int mt = 0; mt < 4; ++mt)
            af[mt] = *(const short8*)&sW[(c4 * 128 + wm * 64 + mt * 16 + lx) * 40 + q * 8];
#pragma unroll
        for (int nt = 0; nt < 2; ++nt)
            bfr[nt] = *(const short8*)&sX[(c4 * 64 + wn * 32 + nt * 16 + lx) * 40 + q * 8];
#pragma unroll
        for (int mt = 0; mt < 4; ++mt)
#pragma unroll
            for (int nt = 0; nt < 2; ++nt)
                acc[mt][nt] = __builtin_amdgcn_mfma_f32_16x16x32_bf16(
                    af[mt], bfr[nt], acc[mt][nt], 0, 0, 0);
    }

    for (int mh = 0; mh < 2; ++mh) {
        __syncthreads();
        if (wm == mh) {
#pragma unroll
            for (int mt = 0; mt < 4; ++mt)
#pragma unroll
                for (int nt = 0; nt < 2; ++nt)
#pragma unroll
                    for (int reg = 0; reg < 4; ++reg)
                        sT[(wn * 32 + nt * 16 + lx) * 65 + mt * 16 + q * 4 + reg] =
                            acc[mt][nt][reg];
        }
        __syncthreads();
        for (int i = tid; i < 512; i += 256) {
            int cog = i & 7, px = i >> 3;
            union { short8 v8; u16 u[8]; } pk;
#pragma unroll
            for (int j = 0; j < 8; ++j) {
                int co = mh * 64 + cog * 8 + j;
                pk.u[j] = f2bf(sT[px * 65 + cog * 8 + j] + bias[co]);
            }
            *(short8*)&out[((size_t)(l0 + px)) * 128 + mh * 64 + cog * 8] = pk.v8;
        }
    }
}

// ---------------------------------------------------------------------------
// attn logits GEMM (MFMA) + bias + scale + softmax over q(9), v2:
//  * 128 px per block: grid (72, 4, 8) = 2304 blocks, block 256 (4 waves,
//    each 32 px x 96 rows: acc[2][6], 48 MFMA/wave between barriers).
//  * sX (32,768 B) and sW (24,576 B) staged via global_load_lds(16B) with
//    granule-slot swizzle (q+(row>>1))&3 -> 2-way ds_read_b128 (free).
//    sW source is pre-swizzled (cast_attn_w), so its stage is linear bulk.
//  * LDS 57,344 B -> 2 blocks/CU. Epilogue sL [128][97] f32 reuses smem.
// ---------------------------------------------------------------------------
__global__ __launch_bounds__(256, 2) void attn_mfma(
    const u16* __restrict__ fgb, const u16* __restrict__ awp,
    const float* __restrict__ ab, u16* __restrict__ A)
{
    const int lt = blockIdx.x, h = blockIdx.y, b = blockIdx.z;
    const int l0 = lt * 128;
    const int tid = threadIdx.x, lane = tid & 63, wv = tid >> 6;
    const int lx = lane & 15, q = lane >> 4;

    __shared__ __align__(16) char smem[57344];
    float* sL = (float*)smem;            // epilogue logits [128][97] (49,664 B)

    // ---- stage sX: [c4 4][px 128][4 slots][16B] = 2048 granules ----
    const u16* fb = fgb + ((size_t)b * LPIX + l0) * 128;
#pragma unroll
    for (int i = 0; i < 8; ++i) {
        int gg = i * 256 + tid;
        int c4 = gg >> 9, r = gg & 511, px = r >> 2, s = r & 3;
        int qq = (s - (px >> 1)) & 3;
        g2lds16(&fb[(size_t)px * 128 + c4 * 32 + qq * 8],
                (char*)smem + (i * 256 + wv * 64) * 16);
    }
    // ---- stage sW: 1536 granules, pre-swizzled linear source ----
    const u16* wb = awp + (size_t)h * 1536 * 8;
#pragma unroll
    for (int i = 0; i < 6; ++i) {
        g2lds16(&wb[(size_t)(i * 256 + tid) * 8],
                (char*)smem + 32768 + (i * 256 + wv * 64) * 16);
    }
    asm volatile("s_waitcnt vmcnt(0)" ::: "memory");
    __builtin_amdgcn_s_barrier();
    asm volatile("" ::: "memory");

    f32x4 acc[2][6];
#pragma unroll
    for (int nt = 0; nt < 2; ++nt)
#pragma unroll
        for (int j = 0; j < 6; ++j) acc[nt][j] = (f32x4){0.f, 0.f, 0.f, 0.f};

#pragma unroll
    for (int c4 = 0; c4 < 4; ++c4) {
        short8 af[2], bfr[6];
#pragma unroll
        for (int nt = 0; nt < 2; ++nt) {
            int px = wv * 32 + nt * 16 + lx;
            af[nt] = *(const short8*)((const char*)smem + c4 * 8192 + px * 64
                                      + (((q + (px >> 1)) & 3) << 4));
        }
#pragma unroll
        for (int j = 0; j < 6; ++j) {
            int rr = j * 16 + lx;
            bfr[j] = *(const short8*)((const char*)smem + 32768 + c4 * 6144 + rr * 64
                                      + (((q + (rr >> 1)) & 3) << 4));
        }
#pragma unroll
        for (int nt = 0; nt < 2; ++nt)
#pragma unroll
            for (int j = 0; j < 6; ++j)
                acc[nt][j] = __builtin_amdgcn_mfma_f32_16x16x32_bf16(
                    af[nt], bfr[j], acc[nt][j], 0, 0, 0);
    }

    __syncthreads();   // done reading sX/sW; reuse as sL
#pragma unroll
    for (int nt = 0; nt < 2; ++nt)
#pragma unroll
        for (int j = 0; j < 6; ++j)
#pragma unroll
            for (int reg = 0; reg < 4; ++reg)
                sL[(wv * 32 + nt * 16 + q * 4 + reg) * 97 + j * 16 + lx] =
                    acc[nt][j][reg];
    __syncthreads();

    for (int t = tid; t < 1152; t += 256) {
        int px = t & 127, p = t >> 7;
        const int rbase = h * 81 + p * 9;
        float lg[9], m = -1e30f;
#pragma unroll
        for (int qq = 0; qq < 9; ++qq) {
            lg[qq] = (sL[px * 97 + p * 9 + qq] + ab[rbase + qq]) * kScale;
            m = fmaxf(m, lg[qq]);
        }
        float s = 0.f;
#pragma unroll
        for (int qq = 0; qq < 9; ++qq) { lg[qq] = __expf(lg[qq] - m); s += lg[qq]; }
        float inv = 1.f / s;
        u16* Ab = &A[(((size_t)(b * 4 + h) * 9 + p) * 9) * LPIX + l0 + px];
#pragma unroll
        for (int qq = 0; qq < 9; ++qq) Ab[(size_t)qq * LPIX] = f2bf(lg[qq] * inv);
    }
}

// ---------------------------------------------------------------------------
// fused einsum + fold (5x5 stencil collapse).
// Block 384 = one head x 4 full rows (384 px). Coalesced A reads (lane=px),
// v staged per-head in LDS (rows y0-2..y0+5 x 96 x 32ch bf16 = 49,152 B).
// grid (24 y-tiles, 4 h, 8 b).
// ---------------------------------------------------------------------------
__global__ __launch_bounds__(384, 4) void attn_fold(
    const u16* __restrict__ A, const u16* __restrict__ v,
    u16* __restrict__ out)
{
    const int yt = blockIdx.x, h = blockIdx.y, b = blockIdx.z;
    const int y0 = yt * 4;
    const int tid = threadIdx.x;          // 0..383
    const int yl  = tid / 96;             // 0..3
    const int x   = tid - yl * 96;
    const int y   = y0 + yl;
    const int l   = y * 96 + x;

    __shared__ u16 sV[8 * 96 * 32];       // [r 8][xx 96][c 32] bf16 = 49,152 B

    // ---- stage v rows y0-2 .. y0+5 (this head's 32 ch) ----
    const u16* vb = v + (size_t)b * LPIX * 128 + h * 32;
    for (int t = tid; t < 3072; t += 384) {
        int k = t & 3, s = t >> 2;        // s = r*96+xx, k = uint4 within 64B
        int r = s / 96, xx = s - r * 96;
        int gy = y0 - 2 + r;
        uint4 uu = make_uint4(0u, 0u, 0u, 0u);
        if ((unsigned)gy < 96u)
            uu = *(const uint4*)&vb[(size_t)(gy * 96 + xx) * 128 + k * 8];
        *(uint4*)&sV[(size_t)s * 32 + k * 8] = uu;
    }

    // ---- stencil S[5][5] from 9 taps x 9 q of A (coalesced bf16 reads) ----
    float S[25];
#pragma unroll
    for (int i = 0; i < 25; ++i) S[i] = 0.f;

    const u16* Ab = A + ((size_t)(b * 4 + h) * 81) * (size_t)LPIX;
#pragma unroll
    for (int ki = 0; ki < 3; ++ki) {
        const int ly = y + 1 - ki;
        const bool vy = ((unsigned)ly < 96u);
#pragma unroll
        for (int kj = 0; kj < 3; ++kj) {
            const int lx2 = x + 1 - kj;
            if (vy && (unsigned)lx2 < 96u) {
                const u16* Ap = Ab + (size_t)(ki * 3 + kj) * 9 * (size_t)LPIX
                              + (ly * 96 + lx2);
#pragma unroll
                for (int qq = 0; qq < 9; ++qq) {
                    const int qi = qq / 3, qj = qq - qi * 3;
                    S[(qi - ki + 2) * 5 + (qj - kj + 2)] += bf2f(Ap[(size_t)qq * LPIX]);
                }
            }
        }
    }

    __syncthreads();   // staging complete before LDS reads

    // ---- 5x5 stencil over LDS v tile ----
    float acc[32];
#pragma unroll
    for (int c = 0; c < 32; ++c) acc[c] = 0.f;

#pragma unroll
    for (int oy = 0; oy < 5; ++oy) {
        const int r = yl + oy;            // LDS row: gy = y0-2+r = y+oy-2
#pragma unroll
        for (int ox = 0; ox < 5; ++ox) {
            const int xx = x + ox - 2;
            if ((unsigned)xx >= 96u) continue;
            const float sc = S[oy * 5 + ox];
            const u16* vp = &sV[(size_t)(r * 96 + xx) * 32];
#pragma unroll
            for (int c8 = 0; c8 < 4; ++c8) {
                const uint4 uu = *(const uint4*)&vp[c8 * 8];
                acc[c8 * 8 + 0] = fmaf(sc, __uint_as_float(uu.x << 16),          acc[c8 * 8 + 0]);
                acc[c8 * 8 + 1] = fmaf(sc, __uint_as_float(uu.x & 0xffff0000u), acc[c8 * 8 + 1]);
                acc[c8 * 8 + 2] = fmaf(sc, __uint_as_float(uu.y << 16),          acc[c8 * 8 + 2]);
                acc[c8 * 8 + 3] = fmaf(sc, __uint_as_float(uu.y & 0xffff0000u), acc[c8 * 8 + 3]);
                acc[c8 * 8 + 4] = fmaf(sc, __uint_as_float(uu.z << 16),          acc[c8 * 8 + 4]);
                acc[c8 * 8 + 5] = fmaf(sc, __uint_as_float(uu.z & 0xffff0000u), acc[c8 * 8 + 5]);
                acc[c8 * 8 + 6] = fmaf(sc, __uint_as_float(uu.w << 16),          acc[c8 * 8 + 6]);
                acc[c8 * 8 + 7] = fmaf(sc, __uint_as_float(uu.w & 0xffff0000u), acc[c8 * 8 + 7]);
            }
        }
    }

    u16* ob = &out[((size_t)b * LPIX + l) * 128 + h * 32];
#pragma unroll
    for (int gidx = 0; gidx < 4; ++gidx) {
        union { short8 v8; u16 u[8]; } pk;
#pragma unroll
        for (int j = 0; j < 8; ++j) pk.u[j] = f2bf(acc[gidx * 8 + j]);
        *(short8*)&ob[gidx * 8] = pk.v8;
    }
}

// ---------------------------------------------------------------------------
extern "C" void kernel_launch(void* const* d_in, const int* in_sizes, int n_in,
                              void* d_out, int out_size, void* d_ws, size_t ws_size,
                              hipStream_t stream)
{
    const float* x    = (const float*)d_in[0];
    const float* fg   = (const float*)d_in[1];
    const float* c1w  = (const float*)d_in[2];
    const float* bn1g = (const float*)d_in[3];
    const float* bn1b = (const float*)d_in[4];
    const float* c2w  = (const float*)d_in[5];
    const float* bn2g = (const float*)d_in[6];
    const float* bn2b = (const float*)d_in[7];
    const float* vw   = (const float*)d_in[8];
    const float* vb   = (const float*)d_in[9];
    const float* aw   = (const float*)d_in[10];
    const float* abv  = (const float*)d_in[11];
    const float* pw   = (const float*)d_in[12];
    const float* pb   = (const float*)d_in[13];
    const float* c3w  = (const float*)d_in[14];
    const float* bn3g = (const float*)d_in[15];
    const float* bn3b = (const float*)d_in[16];
    const float* c4w  = (const float*)d_in[17];
    const float* bn4g = (const float*)d_in[18];
    const float* bn4b = (const float*)d_in[19];

    char* wsp = (char*)d_ws;
    size_t off = 0;
    auto carve = [&](size_t bytes) {
        void* pp = wsp + off;
        off += (bytes + 255) & ~(size_t)255;
        return pp;
    };
    u16*   xb   = (u16*)carve((size_t)8 * LPIX * 64 * 2);     // x NHWC bf16
    u16*   fgb  = (u16*)carve((size_t)8 * LPIX * 128 * 2);    // fg NHWC bf16
    u16*   actA = (u16*)carve((size_t)8 * LPIX * 128 * 2);
    u16*   actB = (u16*)carve((size_t)8 * LPIX * 128 * 2);
    u16*   Abuf = (u16*)carve((size_t)8 * 324 * LPIX * 2);    // A bf16
    u16*   w1p  = (u16*)carve((size_t)9 * 2 * 128 * 32 * 2);
    u16*   w2p  = (u16*)carve((size_t)9 * 4 * 128 * 32 * 2);
    u16*   w3p  = (u16*)carve((size_t)9 * 4 * 128 * 32 * 2);
    u16*   w4p  = (u16*)carve((size_t)9 * 4 * 128 * 32 * 2);
    u16*   vwp  = (u16*)carve((size_t)128 * 128 * 2);
    u16*   pwp  = (u16*)carve((size_t)128 * 128 * 2);
    u16*   awp  = (u16*)carve((size_t)4 * 1536 * 8 * 2);      // pre-swizzled attn W

    // --- pre-casts ---
    cast_nchw_nhwc<64><<<dim3(HW, 8), 256, 0, stream>>>(x, xb);
    cast_nchw_nhwc<128><<<dim3(HW, 8), 256, 0, stream>>>(fg, fgb);
    cast_conv_w<<<(9 * 64 * 128 + 255) / 256, 256, 0, stream>>>(c1w, w1p, 64);
    cast_conv_w<<<(9 * 128 * 128 + 255) / 256, 256, 0, stream>>>(c2w, w2p, 128);
    cast_conv_w<<<(9 * 128 * 128 + 255) / 256, 256, 0, stream>>>(c3w, w3p, 128);
    cast_conv_w<<<(9 * 128 * 128 + 255) / 256, 256, 0, stream>>>(c4w, w4p, 128);
    cast_mat<<<(16384 + 255) / 256, 256, 0, stream>>>(vw, vwp, 16384);
    cast_mat<<<(16384 + 255) / 256, 256, 0, stream>>>(pw, pwp, 16384);
    cast_attn_w<<<192, 256, 0, stream>>>(aw, awp);

    // --- pipeline ---
    conv_gemm<64, false><<<dim3(64, 8), 192, 0, stream>>>(xb, w1p, bn1g, bn1b, actA);
    conv_gemm<128, false><<<dim3(64, 8), 192, 0, stream>>>(actA, w2p, bn2g, bn2b, actB);
    linear_mfma<<<1152, 256, 0, stream>>>(actB, vwp, vb, actA);                 // v
    attn_mfma<<<dim3(72, 4, 8), 256, 0, stream>>>(fgb, awp, abv, Abuf);
    attn_fold<<<dim3(24, 4, 8), 384, 0, stream>>>(Abuf, actA, actB);            // folded
    linear_mfma<<<1152, 256, 0, stream>>>(actB, pwp, pb, actA);                 // p
    conv_gemm<128, false><<<dim3(64, 8), 192, 0, stream>>>(actA, w3p, bn3g, bn3b, actB);
    conv_gemm<128, true><<<dim3(64, 8), 192, 0, stream>>>(actB, w4p, bn4g, bn4b, d_out);
}

// Round 6
// 385.028 us; speedup vs baseline: 1.2372x; 1.2113x over previous
//
#include <hip/hip_runtime.h>
#include <math.h>

typedef __attribute__((ext_vector_type(8))) short short8;
typedef __attribute__((ext_vector_type(4))) float f32x4;
typedef unsigned short u16;
typedef unsigned int u32;

#define HW   96
#define LPIX 9216
static constexpr float kScale = 0.17677669529663687f;  // 1/sqrt(32)

__device__ inline u16 f2bf(float f) {
    u32 x = __float_as_uint(f);
    return (u16)((x + 0x7fffu + ((x >> 16) & 1u)) >> 16);   // RNE
}
__device__ inline float bf2f(u16 v) { return __uint_as_float((u32)v << 16); }

// global -> LDS direct copy, 16B per lane. LDS dest is wave-uniform base +
// lane*16 (HW semantics); global src is per-lane.
typedef __attribute__((address_space(1))) const void gas_t;
typedef __attribute__((address_space(3))) void las_t;
__device__ __forceinline__ void g2lds16(const void* g, void* l) {
    __builtin_amdgcn_global_load_lds((gas_t*)g, (las_t*)l, 16, 0, 0);
}

// counted vmcnt wait (loads stay in flight) + scheduling fence (rule #18)
#define WAITV(n) do {                                                   \
        asm volatile("s_waitcnt vmcnt(" #n ")" ::: "memory");           \
        __builtin_amdgcn_sched_barrier(0);                              \
    } while (0)
#define SFENCE() __builtin_amdgcn_sched_barrier(0)

// ---------------------------------------------------------------------------
// NCHW fp32 -> NHWC bf16 transpose-cast. grid (96 y, 8 b), block 256.
// ---------------------------------------------------------------------------
template <int C>
__global__ __launch_bounds__(256) void cast_nchw_nhwc(
    const float* __restrict__ in, u16* __restrict__ out)
{
    const int y = blockIdx.x, b = blockIdx.y, tid = threadIdx.x;
    __shared__ float sT[HW * C];
    for (int i = tid; i < HW * C; i += 256) {
        int c = i / HW, xx = i - c * HW;
        sT[xx * C + c] = in[(((size_t)b * C + c) * HW + y) * HW + xx];
    }
    __syncthreads();
    for (int i = tid; i < HW * (C / 8); i += 256) {
        int c8 = i % (C / 8), xx = i / (C / 8);
        union { short8 v8; u16 u[8]; } pk;
#pragma unroll
        for (int j = 0; j < 8; ++j) pk.u[j] = f2bf(sT[xx * C + c8 * 8 + j]);
        *(short8*)&out[(((size_t)b * HW + y) * HW + xx) * C + c8 * 8] = pk.v8;
    }
}

// ---------------------------------------------------------------------------
// conv weights [co 128][ci CIN][3][3] fp32 -> v4 granule layout:
//   [c NC][f 9][ch 2][m 64][s 4][e 8]   (granule = 16B = 8 bf16 of ci)
//   ci = c*32 + ((s - (m>>1))&3)*8 + e  (slot rotation = 2-way-free ds_read)
// ---------------------------------------------------------------------------
__global__ void cast_conv_w(const float* __restrict__ w, u16* __restrict__ wp, int CIN)
{
    int n = 9 * CIN * 128;
    int i = blockIdx.x * 256 + threadIdx.x;
    if (i >= n) return;
    int e  = i & 7;
    int gr = i >> 3;                 // granule index
    int c  = gr / 4608;              // 32-ci chunk
    int gi = gr - c * 4608;
    int f  = gi >> 9;
    int rr = gi & 511;
    int ch = rr >> 8;
    int m  = (rr >> 2) & 63;
    int s  = rr & 3;
    int qq = (s - (m >> 1)) & 3;
    int co = ch * 64 + m;
    int ci = c * 32 + qq * 8 + e;
    wp[i] = f2bf(w[(size_t)(co * CIN + ci) * 9 + f]);
}

// ---------------------------------------------------------------------------
// attn weights [324][128] fp32 -> pre-swizzled granule layout for direct
// global_load_lds staging in attn_mfma (see R3).
// ---------------------------------------------------------------------------
__global__ void cast_attn_w(const float* __restrict__ aw, u16* __restrict__ wp)
{
    int i = blockIdx.x * 256 + threadIdx.x;
    if (i >= 4 * 1536 * 8) return;
    int e = i & 7;
    int g = i >> 3;
    int h = g / 1536, r = g - h * 1536;
    int c4 = r / 384, r2 = r - c4 * 384;
    int rr = r2 >> 2, s = r2 & 3;
    int qq = (s - (rr >> 1)) & 3;
    int ci = c4 * 32 + qq * 8 + e;
    float v = (rr < 81) ? aw[(size_t)(h * 81 + rr) * 128 + ci] : 0.f;
    wp[i] = f2bf(v);
}

// dense matrix fp32 -> bf16 (same layout)
__global__ void cast_mat(const float* __restrict__ in, u16* __restrict__ out, int n)
{
    int i = blockIdx.x * 256 + threadIdx.x;
    if (i < n) out[i] = f2bf(in[i]);
}

// ---------------------------------------------------------------------------
// conv3x3 + BN + ReLU, v4.1: pipelined full-co blocks, hardened pipeline.
//  * block = 384 thr (6 waves: ch 2 co-halves x r 3 rows), wave M64 x N96.
//  * grid (32, 8) = 256 blocks = exactly 1/CU. LDS 135.2 KB.
//  * halo staged ONCE per block, double-buffered (480 rows x 64B each buf).
//  * per chunk: { 9 taps x 24 MFMA } -> lgkm drain + barrier ->
//    STAGE_W(c+1) -> STAGE_H(c+2) -> vmcnt(5) (leaves h_{c+2} in flight
//    across the next compute phase) -> barrier. Group order pinned with
//    sched_barrier(0); single counted wait needs only group-level order.
// ---------------------------------------------------------------------------
template <int CIN, bool OUT_F32>
__global__ __launch_bounds__(384, 1) void conv_gemm(
    const u16* __restrict__ in, const u16* __restrict__ wp,
    const float* __restrict__ g, const float* __restrict__ be, void* outv)
{
    constexpr int NC   = CIN / 32;       // 32-ci chunks (2 or 4)
    constexpr int WBYT = 73728;          // weights: 4608 granules x 16B
    constexpr int HBYT = 30720;          // halo buf: 480 rows x 64B

    const int bx = blockIdx.x;           // 0..31
    const int b  = blockIdx.y;
    const int y0 = bx * 3;               // rows y0..y0+2
    const int l0 = y0 * 96;

    const int tid = threadIdx.x, lane = tid & 63, wv = tid >> 6;  // wv 0..5
    const int ch = wv & 1, r = wv >> 1;  // co-half, row
    const int lx = lane & 15, q = lane >> 4;

    __shared__ __align__(16) char smem[WBYT + 2 * HBYT + 64];   // 135,232 B
    float* sT = (float*)smem;            // epilogue bf16 path [144][130]
    float* sF = (float*)smem;            // epilogue f32 path [128][148]

    const int aoff = lx * 64 + (((q + (lx >> 1)) & 3) << 4);
    const int pb   = r * 96 + lx;

    f32x4 acc[4][6];
#pragma unroll
    for (int mt = 0; mt < 4; ++mt)
#pragma unroll
        for (int nt = 0; nt < 6; ++nt) acc[mt][nt] = (f32x4){0.f, 0.f, 0.f, 0.f};

    const u16* inb = in + (size_t)b * LPIX * CIN;

    auto STAGE_W = [&](int c) {          // 12 uniform issues/thread
#pragma unroll
        for (int j = 0; j < 12; ++j) {
            g2lds16(&wp[((size_t)c * 4608 + j * 384 + tid) * 8],
                    (char*)smem + (j * 384 + wv * 64) * 16);
        }
    };
    auto STAGE_H = [&](int c, int buf) { // 5 uniform issues/thread
#pragma unroll
        for (int i = 0; i < 5; ++i) {
            int gi = i * 384 + tid;      // 0..1919
            int p  = gi >> 2, s = gi & 3;
            int qq = (s - (p >> 1)) & 3;
            int lh = l0 - 96 + p;
            lh = lh < 0 ? 0 : (lh >= LPIX ? LPIX - 1 : lh);
            g2lds16(&inb[(size_t)lh * CIN + c * 32 + qq * 8],
                    (char*)smem + WBYT + buf * HBYT + (i * 384 + wv * 64) * 16);
        }
    };
    auto TAP = [&](int f, int hbuf) {
        const int dy = f / 3 - 1, dx = f % 3 - 1;
        const int off = dy * 96 + dx + 97;           // [0,194]
        const bool vy = (unsigned)(y0 + r + dy) < 96u;
        const char* hb = (const char*)smem + WBYT + hbuf * HBYT;
        short8 af[4], bfr[6];
#pragma unroll
        for (int mt = 0; mt < 4; ++mt)
            af[mt] = *(const short8*)((const char*)smem + (f * 2 + ch) * 4096
                                      + mt * 1024 + aoff);
#pragma unroll
        for (int nt = 0; nt < 6; ++nt) {
            int pm = pb + nt * 16 + off - 1;         // staged-row index (-1..480)
            int slot = (q + (pm >> 1)) & 3;
            short8 t8 = *(const short8*)(hb + pm * 64 + slot * 16);
            bool ok = vy & ((unsigned)(nt * 16 + lx + dx) < 96u);
            bfr[nt] = ok ? t8 : (short8){0, 0, 0, 0, 0, 0, 0, 0};
        }
#pragma unroll
        for (int mt = 0; mt < 4; ++mt)
#pragma unroll
            for (int nt = 0; nt < 6; ++nt)
                acc[mt][nt] = __builtin_amdgcn_mfma_f32_16x16x32_bf16(
                    af[mt], bfr[nt], acc[mt][nt], 0, 0, 0);
    };

    // ---- prologue: stage chunk 0 (halo+weights) and chunk 1 halo ----
    STAGE_H(0, 0);
    SFENCE();
    STAGE_W(0);
    SFENCE();
    if (NC > 1) STAGE_H(1, 1);
    SFENCE();
    if (NC > 1) { WAITV(5); } else { WAITV(0); }   // h0+w0 landed; h1 flies
    __builtin_amdgcn_s_barrier();
    asm volatile("" ::: "memory");

#pragma unroll
    for (int c = 0; c < NC; ++c) {
        const int hbuf = c & 1;
        TAP(0, hbuf); TAP(1, hbuf); TAP(2, hbuf);
        TAP(3, hbuf); TAP(4, hbuf); TAP(5, hbuf);
        TAP(6, hbuf); TAP(7, hbuf); TAP(8, hbuf);
        if (c + 1 < NC) {
            // all waves done reading weights_c and halo buf (c&1)
            asm volatile("s_waitcnt lgkmcnt(0)" ::: "memory");
            __builtin_amdgcn_s_barrier();
            asm volatile("" ::: "memory");
            STAGE_W(c + 1);                          // overwrite weight region
            SFENCE();
            if (c + 2 < NC) STAGE_H(c + 2, c & 1);   // overwrite halo buf c&1
            SFENCE();
            // outstanding: h_{c+1}(5 old) + w_{c+1}(12) [+ h_{c+2}(5)]
            if (c + 2 < NC) { WAITV(5); } else { WAITV(0); }
            __builtin_amdgcn_s_barrier();
            asm volatile("" ::: "memory");
        }
    }

    // ---- epilogue ----
    asm volatile("s_waitcnt lgkmcnt(0) vmcnt(0)" ::: "memory");
    __builtin_amdgcn_s_barrier();
    asm volatile("" ::: "memory");

    const float rs = rsqrtf(1.f + 1e-5f);
    if (OUT_F32) {
        float* out = (float*)outv;
#pragma unroll
        for (int hh = 0; hh < 2; ++hh) {               // two 48-px halves
            if (hh) { __syncthreads(); }
#pragma unroll
            for (int mt = 0; mt < 4; ++mt)
#pragma unroll
                for (int nn = 0; nn < 3; ++nn) {
                    int nt = hh * 3 + nn;
#pragma unroll
                    for (int reg = 0; reg < 4; ++reg)
                        sF[(ch * 64 + mt * 16 + q * 4 + reg) * 148
                           + r * 48 + nn * 16 + lx] = acc[mt][nt][reg];
                }
            __syncthreads();
            for (int i = tid; i < 4608; i += 384) {
                int co = i / 36, r2 = i - co * 36;
                int wrr = r2 / 12, j = r2 - wrr * 12;
                float sc = g[co] * rs, bb = be[co];
                f32x4 vv = *(const f32x4*)&sF[co * 148 + wrr * 48 + j * 4];
#pragma unroll
                for (int e = 0; e < 4; ++e) vv[e] = fmaxf(fmaf(vv[e], sc, bb), 0.f);
                *(f32x4*)&out[((size_t)b * 128 + co) * LPIX
                              + (y0 + wrr) * 96 + hh * 48 + j * 4] = vv;
            }
            if (!hh) __syncthreads();
        }
    } else {
        u16* out = (u16*)outv;
#pragma unroll
        for (int hh = 0; hh < 2; ++hh) {               // two 48-px halves
            if (hh) { __syncthreads(); }
#pragma unroll
            for (int mt = 0; mt < 4; ++mt)
#pragma unroll
                for (int nn = 0; nn < 3; ++nn) {
                    int nt = hh * 3 + nn;
#pragma unroll
                    for (int reg = 0; reg < 4; ++reg)
                        sT[(r * 48 + nn * 16 + lx) * 130
                           + ch * 64 + mt * 16 + q * 4 + reg] = acc[mt][nt][reg];
                }
            __syncthreads();
            for (int i = tid; i < 2304; i += 384) {
                int cog = i & 15, pxl = i >> 4;        // 16 co-groups x 144 px
                int wrr = pxl / 48, ofs = pxl - wrr * 48;
                int l = (y0 + wrr) * 96 + hh * 48 + ofs;
                union { short8 v8; u16 u[8]; } pk;
#pragma unroll
                for (int j = 0; j < 8; ++j) {
                    int co = cog * 8 + j;
                    pk.u[j] = f2bf(fmaxf(fmaf(sT[pxl * 130 + cog * 8 + j],
                                              g[co] * rs, be[co]), 0.f));
                }
                *(short8*)&out[((size_t)b * LPIX + l) * 128 + cog * 8] = pk.v8;
            }
            if (!hh) __syncthreads();
        }
    }
}

// ---------------------------------------------------------------------------
// 128->128 linear + bias via MFMA. in/out NHWC-flat bf16 [b*L][128].
// grid 1152 (64 px per block), block 256 (2x2 waves: M=64 x N=32).
// ---------------------------------------------------------------------------
__global__ __launch_bounds__(256) void linear_mfma(
    const u16* __restrict__ in, const u16* __restrict__ wp,
    const float* __restrict__ bias, u16* __restrict__ out)
{
    const int l0 = blockIdx.x * 64;
    const int tid = threadIdx.x, lane = tid & 63, wv = tid >> 6;
    const int wm = wv >> 1, wn = wv & 1;
    const int lx = lane & 15, q = lane >> 4;

    __shared__ char smem[4 * 64 * 40 * 2 + 4 * 128 * 40 * 2];   // 61,440 B
    u16* sX = (u16*)smem;                        // [c4][px 64][32 pitch 40]
    u16* sW = (u16*)(smem + 4 * 64 * 40 * 2);    // [c4][co 128][32 pitch 40]
    float* sT = (float*)smem;                    // epilogue [64][65]

    for (int i = tid; i < 1024; i += 256) {
        int k8 = i & 15, px = i >> 4;
        short8 v = *(const short8*)&in[((size_t)(l0 + px)) * 128 + k8 * 8];
        *(short8*)&sX[((k8 >> 2) * 64 + px) * 40 + (k8 & 3) * 8] = v;
    }
    for (int i = tid; i < 2048; i += 256) {
        int k8 = i & 15, co = i >> 4;
        short8 v = *(const short8*)&wp[(size_t)co * 128 + k8 * 8];
        *(short8*)&sW[((k8 >> 2) * 128 + co) * 40 + (k8 & 3) * 8] = v;
    }
    __syncthreads();

    f32x4 acc[4][2];
#pragma unroll
    for (int mt = 0; mt < 4; ++mt)
#pragma unroll
        for (int nt = 0; nt < 2; ++nt) acc[mt][nt] = (f32x4){0.f, 0.f, 0.f, 0.f};

#pragma unroll
    for (int c4 = 0; c4 < 4; ++c4) {
        short8 af[4], bfr[2];
#pragma unroll
        for (int mt = 0; mt < 4; ++mt)
            af[mt] = *(const short8*)&sW[(c4 * 128 + wm * 64 + mt * 16 + lx) * 40 + q * 8];
#pragma unroll
        for (int nt = 0; nt < 2; ++nt)
            bfr[nt] = *(const short8*)&sX[(c4 * 64 + wn * 32 + nt * 16 + lx) * 40 + q * 8];
#pragma unroll
        for (int mt = 0; mt < 4; ++mt)
#pragma unroll
            for (int nt = 0; nt < 2; ++nt)
                acc[mt][nt] = __builtin_amdgcn_mfma_f32_16x16x32_bf16(
                    af[mt], bfr[nt], acc[mt][nt], 0, 0, 0);
    }

    for (int mh = 0; mh < 2; ++mh) {
        __syncthreads();
        if (wm == mh) {
#pragma unroll
            for (int mt = 0; mt < 4; ++mt)
#pragma unroll
                for (int nt = 0; nt < 2; ++nt)
#pragma unroll
                    for (int reg = 0; reg < 4; ++reg)
                        sT[(wn * 32 + nt * 16 + lx) * 65 + mt * 16 + q * 4 + reg] =
                            acc[mt][nt][reg];
        }
        __syncthreads();
        for (int i = tid; i < 512; i += 256) {
            int cog = i & 7, px = i >> 3;
            union { short8 v8; u16 u[8]; } pk;
#pragma unroll
            for (int j = 0; j < 8; ++j) {
                int co = mh * 64 + cog * 8 + j;
                pk.u[j] = f2bf(sT[px * 65 + cog * 8 + j] + bias[co]);
            }
            *(short8*)&out[((size_t)(l0 + px)) * 128 + mh * 64 + cog * 8] = pk.v8;
        }
    }
}

// ---------------------------------------------------------------------------
// attn logits GEMM (MFMA) + bias + scale + softmax over q(9), v2 (see R3).
// ---------------------------------------------------------------------------
__global__ __launch_bounds__(256, 2) void attn_mfma(
    const u16* __restrict__ fgb, const u16* __restrict__ awp,
    const float* __restrict__ ab, u16* __restrict__ A)
{
    const int lt = blockIdx.x, h = blockIdx.y, b = blockIdx.z;
    const int l0 = lt * 128;
    const int tid = threadIdx.x, lane = tid & 63, wv = tid >> 6;
    const int lx = lane & 15, q = lane >> 4;

    __shared__ __align__(16) char smem[57344];
    float* sL = (float*)smem;            // epilogue logits [128][97] (49,664 B)

    // ---- stage sX: [c4 4][px 128][4 slots][16B] = 2048 granules ----
    const u16* fb = fgb + ((size_t)b * LPIX + l0) * 128;
#pragma unroll
    for (int i = 0; i < 8; ++i) {
        int gg = i * 256 + tid;
        int c4 = gg >> 9, r = gg & 511, px = r >> 2, s = r & 3;
        int qq = (s - (px >> 1)) & 3;
        g2lds16(&fb[(size_t)px * 128 + c4 * 32 + qq * 8],
                (char*)smem + (i * 256 + wv * 64) * 16);
    }
    // ---- stage sW: 1536 granules, pre-swizzled linear source ----
    const u16* wb = awp + (size_t)h * 1536 * 8;
#pragma unroll
    for (int i = 0; i < 6; ++i) {
        g2lds16(&wb[(size_t)(i * 256 + tid) * 8],
                (char*)smem + 32768 + (i * 256 + wv * 64) * 16);
    }
    asm volatile("s_waitcnt vmcnt(0)" ::: "memory");
    __builtin_amdgcn_s_barrier();
    asm volatile("" ::: "memory");

    f32x4 acc[2][6];
#pragma unroll
    for (int nt = 0; nt < 2; ++nt)
#pragma unroll
        for (int j = 0; j < 6; ++j) acc[nt][j] = (f32x4){0.f, 0.f, 0.f, 0.f};

#pragma unroll
    for (int c4 = 0; c4 < 4; ++c4) {
        short8 af[2], bfr[6];
#pragma unroll
        for (int nt = 0; nt < 2; ++nt) {
            int px = wv * 32 + nt * 16 + lx;
            af[nt] = *(const short8*)((const char*)smem + c4 * 8192 + px * 64
                                      + (((q + (px >> 1)) & 3) << 4));
        }
#pragma unroll
        for (int j = 0; j < 6; ++j) {
            int rr = j * 16 + lx;
            bfr[j] = *(const short8*)((const char*)smem + 32768 + c4 * 6144 + rr * 64
                                      + (((q + (rr >> 1)) & 3) << 4));
        }
#pragma unroll
        for (int nt = 0; nt < 2; ++nt)
#pragma unroll
            for (int j = 0; j < 6; ++j)
                acc[nt][j] = __builtin_amdgcn_mfma_f32_16x16x32_bf16(
                    af[nt], bfr[j], acc[nt][j], 0, 0, 0);
    }

    __syncthreads();   // done reading sX/sW; reuse as sL
#pragma unroll
    for (int nt = 0; nt < 2; ++nt)
#pragma unroll
        for (int j = 0; j < 6; ++j)
#pragma unroll
            for (int reg = 0; reg < 4; ++reg)
                sL[(wv * 32 + nt * 16 + q * 4 + reg) * 97 + j * 16 + lx] =
                    acc[nt][j][reg];
    __syncthreads();

    for (int t = tid; t < 1152; t += 256) {
        int px = t & 127, p = t >> 7;
        const int rbase = h * 81 + p * 9;
        float lg[9], m = -1e30f;
#pragma unroll
        for (int qq = 0; qq < 9; ++qq) {
            lg[qq] = (sL[px * 97 + p * 9 + qq] + ab[rbase + qq]) * kScale;
            m = fmaxf(m, lg[qq]);
        }
        float s = 0.f;
#pragma unroll
        for (int qq = 0; qq < 9; ++qq) { lg[qq] = __expf(lg[qq] - m); s += lg[qq]; }
        float inv = 1.f / s;
        u16* Ab = &A[(((size_t)(b * 4 + h) * 9 + p) * 9) * LPIX + l0 + px];
#pragma unroll
        for (int qq = 0; qq < 9; ++qq) Ab[(size_t)qq * LPIX] = f2bf(lg[qq] * inv);
    }
}

// ---------------------------------------------------------------------------
// fused einsum + fold (5x5 stencil collapse). (unchanged)
// ---------------------------------------------------------------------------
__global__ __launch_bounds__(384, 4) void attn_fold(
    const u16* __restrict__ A, const u16* __restrict__ v,
    u16* __restrict__ out)
{
    const int yt = blockIdx.x, h = blockIdx.y, b = blockIdx.z;
    const int y0 = yt * 4;
    const int tid = threadIdx.x;          // 0..383
    const int yl  = tid / 96;             // 0..3
    const int x   = tid - yl * 96;
    const int y   = y0 + yl;
    const int l   = y * 96 + x;

    __shared__ u16 sV[8 * 96 * 32];       // [r 8][xx 96][c 32] bf16 = 49,152 B

    // ---- stage v rows y0-2 .. y0+5 (this head's 32 ch) ----
    const u16* vb = v + (size_t)b * LPIX * 128 + h * 32;
    for (int t = tid; t < 3072; t += 384) {
        int k = t & 3, s = t >> 2;        // s = r*96+xx, k = uint4 within 64B
        int r = s / 96, xx = s - r * 96;
        int gy = y0 - 2 + r;
        uint4 uu = make_uint4(0u, 0u, 0u, 0u);
        if ((unsigned)gy < 96u)
            uu = *(const uint4*)&vb[(size_t)(gy * 96 + xx) * 128 + k * 8];
        *(uint4*)&sV[(size_t)s * 32 + k * 8] = uu;
    }

    // ---- stencil S[5][5] from 9 taps x 9 q of A (coalesced bf16 reads) ----
    float S[25];
#pragma unroll
    for (int i = 0; i < 25; ++i) S[i] = 0.f;

    const u16* Ab = A + ((size_t)(b * 4 + h) * 81) * (size_t)LPIX;
#pragma unroll
    for (int ki = 0; ki < 3; ++ki) {
        const int ly = y + 1 - ki;
        const bool vy = ((unsigned)ly < 96u);
#pragma unroll
        for (int kj = 0; kj < 3; ++kj) {
            const int lx2 = x + 1 - kj;
            if (vy && (unsigned)lx2 < 96u) {
                const u16* Ap = Ab + (size_t)(ki * 3 + kj) * 9 * (size_t)LPIX
                              + (ly * 96 + lx2);
#pragma unroll
                for (int qq = 0; qq < 9; ++qq) {
                    const int qi = qq / 3, qj = qq - qi * 3;
                    S[(qi - ki + 2) * 5 + (qj - kj + 2)] += bf2f(Ap[(size_t)qq * LPIX]);
                }
            }
        }
    }

    __syncthreads();   // staging complete before LDS reads

    // ---- 5x5 stencil over LDS v tile ----
    float acc[32];
#pragma unroll
    for (int c = 0; c < 32; ++c) acc[c] = 0.f;

#pragma unroll
    for (int oy = 0; oy < 5; ++oy) {
        const int r = yl + oy;            // LDS row: gy = y0-2+r = y+oy-2
#pragma unroll
        for (int ox = 0; ox < 5; ++ox) {
            const int xx = x + ox - 2;
            if ((unsigned)xx >= 96u) continue;
            const float sc = S[oy * 5 + ox];
            const u16* vp = &sV[(size_t)(r * 96 + xx) * 32];
#pragma unroll
            for (int c8 = 0; c8 < 4; ++c8) {
                const uint4 uu = *(const uint4*)&vp[c8 * 8];
                acc[c8 * 8 + 0] = fmaf(sc, __uint_as_float(uu.x << 16),          acc[c8 * 8 + 0]);
                acc[c8 * 8 + 1] = fmaf(sc, __uint_as_float(uu.x & 0xffff0000u), acc[c8 * 8 + 1]);
                acc[c8 * 8 + 2] = fmaf(sc, __uint_as_float(uu.y << 16),          acc[c8 * 8 + 2]);
                acc[c8 * 8 + 3] = fmaf(sc, __uint_as_float(uu.y & 0xffff0000u), acc[c8 * 8 + 3]);
                acc[c8 * 8 + 4] = fmaf(sc, __uint_as_float(uu.z << 16),          acc[c8 * 8 + 4]);
                acc[c8 * 8 + 5] = fmaf(sc, __uint_as_float(uu.z & 0xffff0000u), acc[c8 * 8 + 5]);
                acc[c8 * 8 + 6] = fmaf(sc, __uint_as_float(uu.w << 16),          acc[c8 * 8 + 6]);
                acc[c8 * 8 + 7] = fmaf(sc, __uint_as_float(uu.w & 0xffff0000u), acc[c8 * 8 + 7]);
            }
        }
    }

    u16* ob = &out[((size_t)b * LPIX + l) * 128 + h * 32];
#pragma unroll
    for (int gidx = 0; gidx < 4; ++gidx) {
        union { short8 v8; u16 u[8]; } pk;
#pragma unroll
        for (int j = 0; j < 8; ++j) pk.u[j] = f2bf(acc[gidx * 8 + j]);
        *(short8*)&ob[gidx * 8] = pk.v8;
    }
}

// ---------------------------------------------------------------------------
extern "C" void kernel_launch(void* const* d_in, const int* in_sizes, int n_in,
                              void* d_out, int out_size, void* d_ws, size_t ws_size,
                              hipStream_t stream)
{
    const float* x    = (const float*)d_in[0];
    const float* fg   = (const float*)d_in[1];
    const float* c1w  = (const float*)d_in[2];
    const float* bn1g = (const float*)d_in[3];
    const float* bn1b = (const float*)d_in[4];
    const float* c2w  = (const float*)d_in[5];
    const float* bn2g = (const float*)d_in[6];
    const float* bn2b = (const float*)d_in[7];
    const float* vw   = (const float*)d_in[8];
    const float* vb   = (const float*)d_in[9];
    const float* aw   = (const float*)d_in[10];
    const float* abv  = (const float*)d_in[11];
    const float* pw   = (const float*)d_in[12];
    const float* pb   = (const float*)d_in[13];
    const float* c3w  = (const float*)d_in[14];
    const float* bn3g = (const float*)d_in[15];
    const float* bn3b = (const float*)d_in[16];
    const float* c4w  = (const float*)d_in[17];
    const float* bn4g = (const float*)d_in[18];
    const float* bn4b = (const float*)d_in[19];

    char* wsp = (char*)d_ws;
    size_t off = 0;
    auto carve = [&](size_t bytes) {
        void* pp = wsp + off;
        off += (bytes + 255) & ~(size_t)255;
        return pp;
    };
    u16*   xb   = (u16*)carve((size_t)8 * LPIX * 64 * 2);     // x NHWC bf16
    u16*   fgb  = (u16*)carve((size_t)8 * LPIX * 128 * 2);    // fg NHWC bf16
    u16*   actA = (u16*)carve((size_t)8 * LPIX * 128 * 2);
    u16*   actB = (u16*)carve((size_t)8 * LPIX * 128 * 2);
    u16*   Abuf = (u16*)carve((size_t)8 * 324 * LPIX * 2);    // A bf16
    u16*   w1p  = (u16*)carve((size_t)9 * 2 * 128 * 32 * 2);
    u16*   w2p  = (u16*)carve((size_t)9 * 4 * 128 * 32 * 2);
    u16*   w3p  = (u16*)carve((size_t)9 * 4 * 128 * 32 * 2);
    u16*   w4p  = (u16*)carve((size_t)9 * 4 * 128 * 32 * 2);
    u16*   vwp  = (u16*)carve((size_t)128 * 128 * 2);
    u16*   pwp  = (u16*)carve((size_t)128 * 128 * 2);
    u16*   awp  = (u16*)carve((size_t)4 * 1536 * 8 * 2);      // pre-swizzled attn W

    // --- pre-casts ---
    cast_nchw_nhwc<64><<<dim3(HW, 8), 256, 0, stream>>>(x, xb);
    cast_nchw_nhwc<128><<<dim3(HW, 8), 256, 0, stream>>>(fg, fgb);
    cast_conv_w<<<(9 * 64 * 128 + 255) / 256, 256, 0, stream>>>(c1w, w1p, 64);
    cast_conv_w<<<(9 * 128 * 128 + 255) / 256, 256, 0, stream>>>(c2w, w2p, 128);
    cast_conv_w<<<(9 * 128 * 128 + 255) / 256, 256, 0, stream>>>(c3w, w3p, 128);
    cast_conv_w<<<(9 * 128 * 128 + 255) / 256, 256, 0, stream>>>(c4w, w4p, 128);
    cast_mat<<<(16384 + 255) / 256, 256, 0, stream>>>(vw, vwp, 16384);
    cast_mat<<<(16384 + 255) / 256, 256, 0, stream>>>(pw, pwp, 16384);
    cast_attn_w<<<192, 256, 0, stream>>>(aw, awp);

    // --- pipeline ---
    conv_gemm<64, false><<<dim3(32, 8), 384, 0, stream>>>(xb, w1p, bn1g, bn1b, actA);
    conv_gemm<128, false><<<dim3(32, 8), 384, 0, stream>>>(actA, w2p, bn2g, bn2b, actB);
    linear_mfma<<<1152, 256, 0, stream>>>(actB, vwp, vb, actA);                 // v
    attn_mfma<<<dim3(72, 4, 8), 256, 0, stream>>>(fgb, awp, abv, Abuf);
    attn_fold<<<dim3(24, 4, 8), 384, 0, stream>>>(Abuf, actA, actB);            // folded
    linear_mfma<<<1152, 256, 0, stream>>>(actB, pwp, pb, actA);                 // p
    conv_gemm<128, false><<<dim3(32, 8), 384, 0, stream>>>(actA, w3p, bn3g, bn3b, actB);
    conv_gemm<128, true><<<dim3(32, 8), 384, 0, stream>>>(actB, w4p, bn4g, bn4b, d_out);
}

// Round 7
// 365.096 us; speedup vs baseline: 1.3048x; 1.0546x over previous
//
#include <hip/hip_runtime.h>
#include <math.h>

typedef __attribute__((ext_vector_type(8))) short short8;
typedef __attribute__((ext_vector_type(4))) float f32x4;
typedef unsigned short u16;
typedef unsigned int u32;

#define HW   96
#define LPIX 9216
static constexpr float kScale = 0.17677669529663687f;  // 1/sqrt(32)

__device__ inline u16 f2bf(float f) {
    u32 x = __float_as_uint(f);
    return (u16)((x + 0x7fffu + ((x >> 16) & 1u)) >> 16);   // RNE
}
__device__ inline float bf2f(u16 v) { return __uint_as_float((u32)v << 16); }

// global -> LDS direct copy, 16B per lane. LDS dest is wave-uniform base +
// lane*16 (HW semantics); global src is per-lane.
typedef __attribute__((address_space(1))) const void gas_t;
typedef __attribute__((address_space(3))) void las_t;
__device__ __forceinline__ void g2lds16(const void* g, void* l) {
    __builtin_amdgcn_global_load_lds((gas_t*)g, (las_t*)l, 16, 0, 0);
}

// counted vmcnt wait (loads stay in flight) + scheduling fence (rule #18)
#define WAITV(n) do {                                                   \
        asm volatile("s_waitcnt vmcnt(" #n ")" ::: "memory");           \
        __builtin_amdgcn_sched_barrier(0);                              \
    } while (0)
#define SFENCE() __builtin_amdgcn_sched_barrier(0)

// ---------------------------------------------------------------------------
// NCHW fp32 -> NHWC bf16 transpose-cast. grid (96 y, 8 b), block 256.
// ---------------------------------------------------------------------------
template <int C>
__global__ __launch_bounds__(256) void cast_nchw_nhwc(
    const float* __restrict__ in, u16* __restrict__ out)
{
    const int y = blockIdx.x, b = blockIdx.y, tid = threadIdx.x;
    __shared__ float sT[HW * C];
    for (int i = tid; i < HW * C; i += 256) {
        int c = i / HW, xx = i - c * HW;
        sT[xx * C + c] = in[(((size_t)b * C + c) * HW + y) * HW + xx];
    }
    __syncthreads();
    for (int i = tid; i < HW * (C / 8); i += 256) {
        int c8 = i % (C / 8), xx = i / (C / 8);
        union { short8 v8; u16 u[8]; } pk;
#pragma unroll
        for (int j = 0; j < 8; ++j) pk.u[j] = f2bf(sT[xx * C + c8 * 8 + j]);
        *(short8*)&out[(((size_t)b * HW + y) * HW + xx) * C + c8 * 8] = pk.v8;
    }
}

// ---------------------------------------------------------------------------
// conv weights [co 128][ci CIN][3][3] fp32 -> granule layout:
//   [c NC][f 9][ch 2][m 64][s 4][e 8]   (granule = 16B = 8 bf16 of ci)
//   ci = c*32 + ((s - (m>>1))&3)*8 + e  (slot rotation = 2-way-free ds_read)
// ---------------------------------------------------------------------------
__global__ void cast_conv_w(const float* __restrict__ w, u16* __restrict__ wp, int CIN)
{
    int n = 9 * CIN * 128;
    int i = blockIdx.x * 256 + threadIdx.x;
    if (i >= n) return;
    int e  = i & 7;
    int gr = i >> 3;                 // granule index
    int c  = gr / 4608;              // 32-ci chunk
    int gi = gr - c * 4608;
    int f  = gi >> 9;
    int rr = gi & 511;
    int ch = rr >> 8;
    int m  = (rr >> 2) & 63;
    int s  = rr & 3;
    int qq = (s - (m >> 1)) & 3;
    int co = ch * 64 + m;
    int ci = c * 32 + qq * 8 + e;
    wp[i] = f2bf(w[(size_t)(co * CIN + ci) * 9 + f]);
}

// ---------------------------------------------------------------------------
// attn weights [324][128] fp32 -> pre-swizzled granule layout for direct
// global_load_lds staging in attn_mfma (see R3).
// ---------------------------------------------------------------------------
__global__ void cast_attn_w(const float* __restrict__ aw, u16* __restrict__ wp)
{
    int i = blockIdx.x * 256 + threadIdx.x;
    if (i >= 4 * 1536 * 8) return;
    int e = i & 7;
    int g = i >> 3;
    int h = g / 1536, r = g - h * 1536;
    int c4 = r / 384, r2 = r - c4 * 384;
    int rr = r2 >> 2, s = r2 & 3;
    int qq = (s - (rr >> 1)) & 3;
    int ci = c4 * 32 + qq * 8 + e;
    float v = (rr < 81) ? aw[(size_t)(h * 81 + rr) * 128 + ci] : 0.f;
    wp[i] = f2bf(v);
}

// dense matrix fp32 -> bf16 (same layout)
__global__ void cast_mat(const float* __restrict__ in, u16* __restrict__ out, int n)
{
    int i = blockIdx.x * 256 + threadIdx.x;
    if (i < n) out[i] = f2bf(in[i]);
}

// ---------------------------------------------------------------------------
// conv3x3 + BN + ReLU, v5: 12-wave pipelined blocks (3 waves/SIMD).
//  * block = 768 thr: wv = r(3 rows) x ch(2 co-halves) x half(2 px-halves);
//    wave tile M64 x N48, acc[4][3] (48 VGPR) -> ~130 total, 3 waves/SIMD.
//  * grid (32, 8) = 256 = 1 block/CU. LDS 147.5 KB (weights 73.7 +
//    2 x 36.9 halo dbuf, padded to 576 rows for UNIFORM 3-issue staging --
//    uniformity keeps per-wave vmcnt counts in lockstep).
//  * counted-vmcnt pipeline (T3/T4): per chunk {9 taps x 12 MFMA} ->
//    lgkm(0)+bar -> STAGE_W(c+1)[6] -> STAGE_H(c+2)[3] -> vmcnt(3|0) -> bar.
//    Next-next halo flies across the whole compute phase.
// ---------------------------------------------------------------------------
template <int CIN, bool OUT_F32>
__global__ __launch_bounds__(768, 1) void conv_gemm(
    const u16* __restrict__ in, const u16* __restrict__ wp,
    const float* __restrict__ g, const float* __restrict__ be, void* outv)
{
    constexpr int NC   = CIN / 32;       // 32-ci chunks (2 or 4)
    constexpr int WBYT = 73728;          // weights: 4608 granules x 16B
    constexpr int HBYT = 36864;          // halo buf: 576 rows x 64B (2304 gran)

    const int bx = blockIdx.x;           // 0..31
    const int b  = blockIdx.y;
    const int y0 = bx * 3;               // rows y0..y0+2
    const int l0 = y0 * 96;

    const int tid = threadIdx.x, lane = tid & 63, wv = tid >> 6;  // wv 0..11
    const int half = wv & 1, ch = (wv >> 1) & 1, r = wv >> 2;
    const int lx = lane & 15, q = lane >> 4;

    __shared__ __align__(16) char smem[WBYT + 2 * HBYT];   // 147,456 B
    float* sT = (float*)smem;            // epilogue bf16 path [144][130]
    float* sF = (float*)smem;            // epilogue f32 path [128][148]

    const int aoff = lx * 64 + (((q + (lx >> 1)) & 3) << 4);
    const int pb   = r * 96 + half * 48 + lx;

    f32x4 acc[4][3];
#pragma unroll
    for (int mt = 0; mt < 4; ++mt)
#pragma unroll
        for (int nt = 0; nt < 3; ++nt) acc[mt][nt] = (f32x4){0.f, 0.f, 0.f, 0.f};

    const u16* inb = in + (size_t)b * LPIX * CIN;

    auto STAGE_W = [&](int c) {          // 6 uniform issues/thread
#pragma unroll
        for (int j = 0; j < 6; ++j) {
            g2lds16(&wp[((size_t)c * 4608 + j * 768 + tid) * 8],
                    (char*)smem + (j * 768 + wv * 64) * 16);
        }
    };
    auto STAGE_H = [&](int c, int buf) { // 3 uniform issues/thread (2304 gran)
#pragma unroll
        for (int i = 0; i < 3; ++i) {
            int gi = i * 768 + tid;      // 0..2303
            int p  = gi >> 2, s = gi & 3;
            int qq = (s - (p >> 1)) & 3;
            int lh = l0 - 96 + p;        // rows l0-96 .. l0+479 (clamped)
            lh = lh < 0 ? 0 : (lh >= LPIX ? LPIX - 1 : lh);
            g2lds16(&inb[(size_t)lh * CIN + c * 32 + qq * 8],
                    (char*)smem + WBYT + buf * HBYT + (i * 768 + wv * 64) * 16);
        }
    };
    auto TAP = [&](int f, int hbuf) {
        const int dy = f / 3 - 1, dx = f % 3 - 1;
        const int off = dy * 96 + dx + 96;           // pm = pb + nt*16 + off
        const bool vy = (unsigned)(y0 + r + dy) < 96u;
        const char* hb = (const char*)smem + WBYT + hbuf * HBYT;
        short8 af[4], bfr[3];
#pragma unroll
        for (int mt = 0; mt < 4; ++mt)
            af[mt] = *(const short8*)((const char*)smem + (f * 2 + ch) * 4096
                                      + mt * 1024 + aoff);
#pragma unroll
        for (int nt = 0; nt < 3; ++nt) {
            int pm = pb + nt * 16 + off;             // staged-row idx (-1..479)
            int slot = (q + (pm >> 1)) & 3;
            short8 t8 = *(const short8*)(hb + pm * 64 + slot * 16);
            bool ok = vy & ((unsigned)(half * 48 + nt * 16 + lx + dx) < 96u);
            bfr[nt] = ok ? t8 : (short8){0, 0, 0, 0, 0, 0, 0, 0};
        }
#pragma unroll
        for (int mt = 0; mt < 4; ++mt)
#pragma unroll
            for (int nt = 0; nt < 3; ++nt)
                acc[mt][nt] = __builtin_amdgcn_mfma_f32_16x16x32_bf16(
                    af[mt], bfr[nt], acc[mt][nt], 0, 0, 0);
    };

    // ---- prologue: stage chunk 0 (halo+weights) and chunk 1 halo ----
    STAGE_H(0, 0);
    SFENCE();
    STAGE_W(0);
    SFENCE();
    STAGE_H(1, 1);                       // NC >= 2 always
    SFENCE();
    WAITV(3);                            // h0+w0 landed; h1 flies
    __builtin_amdgcn_s_barrier();
    asm volatile("" ::: "memory");

#pragma unroll
    for (int c = 0; c < NC; ++c) {
        const int hbuf = c & 1;
        TAP(0, hbuf); TAP(1, hbuf); TAP(2, hbuf);
        TAP(3, hbuf); TAP(4, hbuf); TAP(5, hbuf);
        TAP(6, hbuf); TAP(7, hbuf); TAP(8, hbuf);
        if (c + 1 < NC) {
            // all waves done reading weights_c and halo buf (c&1)
            asm volatile("s_waitcnt lgkmcnt(0)" ::: "memory");
            __builtin_amdgcn_s_barrier();
            asm volatile("" ::: "memory");
            STAGE_W(c + 1);                          // overwrite weight region
            SFENCE();
            if (c + 2 < NC) STAGE_H(c + 2, c & 1);   // overwrite halo buf c&1
            SFENCE();
            // outstanding: h_{c+1}(3, landed) + w_{c+1}(6) [+ h_{c+2}(3)]
            if (c + 2 < NC) { WAITV(3); } else { WAITV(0); }
            __builtin_amdgcn_s_barrier();
            asm volatile("" ::: "memory");
        }
    }

    // ---- epilogue ----
    asm volatile("s_waitcnt lgkmcnt(0) vmcnt(0)" ::: "memory");
    __builtin_amdgcn_s_barrier();
    asm volatile("" ::: "memory");

    const float rs = rsqrtf(1.f + 1e-5f);
    if (OUT_F32) {
        float* out = (float*)outv;
#pragma unroll
        for (int hh = 0; hh < 2; ++hh) {               // two 48-px halves
            if (hh) { __syncthreads(); }
            if (half == hh) {
#pragma unroll
                for (int mt = 0; mt < 4; ++mt)
#pragma unroll
                    for (int nt = 0; nt < 3; ++nt)
#pragma unroll
                        for (int reg = 0; reg < 4; ++reg)
                            sF[(ch * 64 + mt * 16 + q * 4 + reg) * 148
                               + r * 48 + nt * 16 + lx] = acc[mt][nt][reg];
            }
            __syncthreads();
            for (int i = tid; i < 4608; i += 768) {
                int co = i / 36, r2 = i - co * 36;
                int wrr = r2 / 12, j = r2 - wrr * 12;
                float sc = g[co] * rs, bb = be[co];
                f32x4 vv = *(const f32x4*)&sF[co * 148 + wrr * 48 + j * 4];
#pragma unroll
                for (int e = 0; e < 4; ++e) vv[e] = fmaxf(fmaf(vv[e], sc, bb), 0.f);
                *(f32x4*)&out[((size_t)b * 128 + co) * LPIX
                              + (y0 + wrr) * 96 + hh * 48 + j * 4] = vv;
            }
            if (!hh) __syncthreads();
        }
    } else {
        u16* out = (u16*)outv;
#pragma unroll
        for (int hh = 0; hh < 2; ++hh) {               // two 48-px halves
            if (hh) { __syncthreads(); }
            if (half == hh) {
#pragma unroll
                for (int mt = 0; mt < 4; ++mt)
#pragma unroll
                    for (int nt = 0; nt < 3; ++nt)
#pragma unroll
                        for (int reg = 0; reg < 4; ++reg)
                            sT[(r * 48 + nt * 16 + lx) * 130
                               + ch * 64 + mt * 16 + q * 4 + reg] = acc[mt][nt][reg];
            }
            __syncthreads();
            for (int i = tid; i < 2304; i += 768) {
                int cog = i & 15, pxl = i >> 4;        // 16 co-groups x 144 px
                int wrr = pxl / 48, ofs = pxl - wrr * 48;
                int l = (y0 + wrr) * 96 + hh * 48 + ofs;
                union { short8 v8; u16 u[8]; } pk;
#pragma unroll
                for (int j = 0; j < 8; ++j) {
                    int co = cog * 8 + j;
                    pk.u[j] = f2bf(fmaxf(fmaf(sT[pxl * 130 + cog * 8 + j],
                                              g[co] * rs, be[co]), 0.f));
                }
                *(short8*)&out[((size_t)b * LPIX + l) * 128 + cog * 8] = pk.v8;
            }
            if (!hh) __syncthreads();
        }
    }
}

// ---------------------------------------------------------------------------
// 128->128 linear + bias via MFMA. in/out NHWC-flat bf16 [b*L][128].
// grid 1152 (64 px per block), block 256 (2x2 waves: M=64 x N=32).
// ---------------------------------------------------------------------------
__global__ __launch_bounds__(256) void linear_mfma(
    const u16* __restrict__ in, const u16* __restrict__ wp,
    const float* __restrict__ bias, u16* __restrict__ out)
{
    const int l0 = blockIdx.x * 64;
    const int tid = threadIdx.x, lane = tid & 63, wv = tid >> 6;
    const int wm = wv >> 1, wn = wv & 1;
    const int lx = lane & 15, q = lane >> 4;

    __shared__ char smem[4 * 64 * 40 * 2 + 4 * 128 * 40 * 2];   // 61,440 B
    u16* sX = (u16*)smem;                        // [c4][px 64][32 pitch 40]
    u16* sW = (u16*)(smem + 4 * 64 * 40 * 2);    // [c4][co 128][32 pitch 40]
    float* sT = (float*)smem;                    // epilogue [64][65]

    for (int i = tid; i < 1024; i += 256) {
        int k8 = i & 15, px = i >> 4;
        short8 v = *(const short8*)&in[((size_t)(l0 + px)) * 128 + k8 * 8];
        *(short8*)&sX[((k8 >> 2) * 64 + px) * 40 + (k8 & 3) * 8] = v;
    }
    for (int i = tid; i < 2048; i += 256) {
        int k8 = i & 15, co = i >> 4;
        short8 v = *(const short8*)&wp[(size_t)co * 128 + k8 * 8];
        *(short8*)&sW[((k8 >> 2) * 128 + co) * 40 + (k8 & 3) * 8] = v;
    }
    __syncthreads();

    f32x4 acc[4][2];
#pragma unroll
    for (int mt = 0; mt < 4; ++mt)
#pragma unroll
        for (int nt = 0; nt < 2; ++nt) acc[mt][nt] = (f32x4){0.f, 0.f, 0.f, 0.f};

#pragma unroll
    for (int c4 = 0; c4 < 4; ++c4) {
        short8 af[4], bfr[2];
#pragma unroll
        for (int mt = 0; mt < 4; ++mt)
            af[mt] = *(const short8*)&sW[(c4 * 128 + wm * 64 + mt * 16 + lx) * 40 + q * 8];
#pragma unroll
        for (int nt = 0; nt < 2; ++nt)
            bfr[nt] = *(const short8*)&sX[(c4 * 64 + wn * 32 + nt * 16 + lx) * 40 + q * 8];
#pragma unroll
        for (int mt = 0; mt < 4; ++mt)
#pragma unroll
            for (int nt = 0; nt < 2; ++nt)
                acc[mt][nt] = __builtin_amdgcn_mfma_f32_16x16x32_bf16(
                    af[mt], bfr[nt], acc[mt][nt], 0, 0, 0);
    }

    for (int mh = 0; mh < 2; ++mh) {
        __syncthreads();
        if (wm == mh) {
#pragma unroll
            for (int mt = 0; mt < 4; ++mt)
#pragma unroll
                for (int nt = 0; nt < 2; ++nt)
#pragma unroll
                    for (int reg = 0; reg < 4; ++reg)
                        sT[(wn * 32 + nt * 16 + lx) * 65 + mt * 16 + q * 4 + reg] =
                            acc[mt][nt][reg];
        }
        __syncthreads();
        for (int i = tid; i < 512; i += 256) {
            int cog = i & 7, px = i >> 3;
            union { short8 v8; u16 u[8]; } pk;
#pragma unroll
            for (int j = 0; j < 8; ++j) {
                int co = mh * 64 + cog * 8 + j;
                pk.u[j] = f2bf(sT[px * 65 + cog * 8 + j] + bias[co]);
            }
            *(short8*)&out[((size_t)(l0 + px)) * 128 + mh * 64 + cog * 8] = pk.v8;
        }
    }
}

// ---------------------------------------------------------------------------
// attn logits GEMM (MFMA) + bias + scale + softmax over q(9), v2 (see R3).
// ---------------------------------------------------------------------------
__global__ __launch_bounds__(256, 2) void attn_mfma(
    const u16* __restrict__ fgb, const u16* __restrict__ awp,
    const float* __restrict__ ab, u16* __restrict__ A)
{
    const int lt = blockIdx.x, h = blockIdx.y, b = blockIdx.z;
    const int l0 = lt * 128;
    const int tid = threadIdx.x, lane = tid & 63, wv = tid >> 6;
    const int lx = lane & 15, q = lane >> 4;

    __shared__ __align__(16) char smem[57344];
    float* sL = (float*)smem;            // epilogue logits [128][97] (49,664 B)

    // ---- stage sX: [c4 4][px 128][4 slots][16B] = 2048 granules ----
    const u16* fb = fgb + ((size_t)b * LPIX + l0) * 128;
#pragma unroll
    for (int i = 0; i < 8; ++i) {
        int gg = i * 256 + tid;
        int c4 = gg >> 9, r = gg & 511, px = r >> 2, s = r & 3;
        int qq = (s - (px >> 1)) & 3;
        g2lds16(&fb[(size_t)px * 128 + c4 * 32 + qq * 8],
                (char*)smem + (i * 256 + wv * 64) * 16);
    }
    // ---- stage sW: 1536 granules, pre-swizzled linear source ----
    const u16* wb = awp + (size_t)h * 1536 * 8;
#pragma unroll
    for (int i = 0; i < 6; ++i) {
        g2lds16(&wb[(size_t)(i * 256 + tid) * 8],
                (char*)smem + 32768 + (i * 256 + wv * 64) * 16);
    }
    asm volatile("s_waitcnt vmcnt(0)" ::: "memory");
    __builtin_amdgcn_s_barrier();
    asm volatile("" ::: "memory");

    f32x4 acc[2][6];
#pragma unroll
    for (int nt = 0; nt < 2; ++nt)
#pragma unroll
        for (int j = 0; j < 6; ++j) acc[nt][j] = (f32x4){0.f, 0.f, 0.f, 0.f};

#pragma unroll
    for (int c4 = 0; c4 < 4; ++c4) {
        short8 af[2], bfr[6];
#pragma unroll
        for (int nt = 0; nt < 2; ++nt) {
            int px = wv * 32 + nt * 16 + lx;
            af[nt] = *(const short8*)((const char*)smem + c4 * 8192 + px * 64
                                      + (((q + (px >> 1)) & 3) << 4));
        }
#pragma unroll
        for (int j = 0; j < 6; ++j) {
            int rr = j * 16 + lx;
            bfr[j] = *(const short8*)((const char*)smem + 32768 + c4 * 6144 + rr * 64
                                      + (((q + (rr >> 1)) & 3) << 4));
        }
#pragma unroll
        for (int nt = 0; nt < 2; ++nt)
#pragma unroll
            for (int j = 0; j < 6; ++j)
                acc[nt][j] = __builtin_amdgcn_mfma_f32_16x16x32_bf16(
                    af[nt], bfr[j], acc[nt][j], 0, 0, 0);
    }

    __syncthreads();   // done reading sX/sW; reuse as sL
#pragma unroll
    for (int nt = 0; nt < 2; ++nt)
#pragma unroll
        for (int j = 0; j < 6; ++j)
#pragma unroll
            for (int reg = 0; reg < 4; ++reg)
                sL[(wv * 32 + nt * 16 + q * 4 + reg) * 97 + j * 16 + lx] =
                    acc[nt][j][reg];
    __syncthreads();

    for (int t = tid; t < 1152; t += 256) {
        int px = t & 127, p = t >> 7;
        const int rbase = h * 81 + p * 9;
        float lg[9], m = -1e30f;
#pragma unroll
        for (int qq = 0; qq < 9; ++qq) {
            lg[qq] = (sL[px * 97 + p * 9 + qq] + ab[rbase + qq]) * kScale;
            m = fmaxf(m, lg[qq]);
        }
        float s = 0.f;
#pragma unroll
        for (int qq = 0; qq < 9; ++qq) { lg[qq] = __expf(lg[qq] - m); s += lg[qq]; }
        float inv = 1.f / s;
        u16* Ab = &A[(((size_t)(b * 4 + h) * 9 + p) * 9) * LPIX + l0 + px];
#pragma unroll
        for (int qq = 0; qq < 9; ++qq) Ab[(size_t)qq * LPIX] = f2bf(lg[qq] * inv);
    }
}

// ---------------------------------------------------------------------------
// fused einsum + fold (5x5 stencil collapse). (unchanged)
// ---------------------------------------------------------------------------
__global__ __launch_bounds__(384, 4) void attn_fold(
    const u16* __restrict__ A, const u16* __restrict__ v,
    u16* __restrict__ out)
{
    const int yt = blockIdx.x, h = blockIdx.y, b = blockIdx.z;
    const int y0 = yt * 4;
    const int tid = threadIdx.x;          // 0..383
    const int yl  = tid / 96;             // 0..3
    const int x   = tid - yl * 96;
    const int y   = y0 + yl;
    const int l   = y * 96 + x;

    __shared__ u16 sV[8 * 96 * 32];       // [r 8][xx 96][c 32] bf16 = 49,152 B

    // ---- stage v rows y0-2 .. y0+5 (this head's 32 ch) ----
    const u16* vb = v + (size_t)b * LPIX * 128 + h * 32;
    for (int t = tid; t < 3072; t += 384) {
        int k = t & 3, s = t >> 2;        // s = r*96+xx, k = uint4 within 64B
        int r = s / 96, xx = s - r * 96;
        int gy = y0 - 2 + r;
        uint4 uu = make_uint4(0u, 0u, 0u, 0u);
        if ((unsigned)gy < 96u)
            uu = *(const uint4*)&vb[(size_t)(gy * 96 + xx) * 128 + k * 8];
        *(uint4*)&sV[(size_t)s * 32 + k * 8] = uu;
    }

    // ---- stencil S[5][5] from 9 taps x 9 q of A (coalesced bf16 reads) ----
    float S[25];
#pragma unroll
    for (int i = 0; i < 25; ++i) S[i] = 0.f;

    const u16* Ab = A + ((size_t)(b * 4 + h) * 81) * (size_t)LPIX;
#pragma unroll
    for (int ki = 0; ki < 3; ++ki) {
        const int ly = y + 1 - ki;
        const bool vy = ((unsigned)ly < 96u);
#pragma unroll
        for (int kj = 0; kj < 3; ++kj) {
            const int lx2 = x + 1 - kj;
            if (vy && (unsigned)lx2 < 96u) {
                const u16* Ap = Ab + (size_t)(ki * 3 + kj) * 9 * (size_t)LPIX
                              + (ly * 96 + lx2);
#pragma unroll
                for (int qq = 0; qq < 9; ++qq) {
                    const int qi = qq / 3, qj = qq - qi * 3;
                    S[(qi - ki + 2) * 5 + (qj - kj + 2)] += bf2f(Ap[(size_t)qq * LPIX]);
                }
            }
        }
    }

    __syncthreads();   // staging complete before LDS reads

    // ---- 5x5 stencil over LDS v tile ----
    float acc[32];
#pragma unroll
    for (int c = 0; c < 32; ++c) acc[c] = 0.f;

#pragma unroll
    for (int oy = 0; oy < 5; ++oy) {
        const int r = yl + oy;            // LDS row: gy = y0-2+r = y+oy-2
#pragma unroll
        for (int ox = 0; ox < 5; ++ox) {
            const int xx = x + ox - 2;
            if ((unsigned)xx >= 96u) continue;
            const float sc = S[oy * 5 + ox];
            const u16* vp = &sV[(size_t)(r * 96 + xx) * 32];
#pragma unroll
            for (int c8 = 0; c8 < 4; ++c8) {
                const uint4 uu = *(const uint4*)&vp[c8 * 8];
                acc[c8 * 8 + 0] = fmaf(sc, __uint_as_float(uu.x << 16),          acc[c8 * 8 + 0]);
                acc[c8 * 8 + 1] = fmaf(sc, __uint_as_float(uu.x & 0xffff0000u), acc[c8 * 8 + 1]);
                acc[c8 * 8 + 2] = fmaf(sc, __uint_as_float(uu.y << 16),          acc[c8 * 8 + 2]);
                acc[c8 * 8 + 3] = fmaf(sc, __uint_as_float(uu.y & 0xffff0000u), acc[c8 * 8 + 3]);
                acc[c8 * 8 + 4] = fmaf(sc, __uint_as_float(uu.z << 16),          acc[c8 * 8 + 4]);
                acc[c8 * 8 + 5] = fmaf(sc, __uint_as_float(uu.z & 0xffff0000u), acc[c8 * 8 + 5]);
                acc[c8 * 8 + 6] = fmaf(sc, __uint_as_float(uu.w << 16),          acc[c8 * 8 + 6]);
                acc[c8 * 8 + 7] = fmaf(sc, __uint_as_float(uu.w & 0xffff0000u), acc[c8 * 8 + 7]);
            }
        }
    }

    u16* ob = &out[((size_t)b * LPIX + l) * 128 + h * 32];
#pragma unroll
    for (int gidx = 0; gidx < 4; ++gidx) {
        union { short8 v8; u16 u[8]; } pk;
#pragma unroll
        for (int j = 0; j < 8; ++j) pk.u[j] = f2bf(acc[gidx * 8 + j]);
        *(short8*)&ob[gidx * 8] = pk.v8;
    }
}

// ---------------------------------------------------------------------------
extern "C" void kernel_launch(void* const* d_in, const int* in_sizes, int n_in,
                              void* d_out, int out_size, void* d_ws, size_t ws_size,
                              hipStream_t stream)
{
    const float* x    = (const float*)d_in[0];
    const float* fg   = (const float*)d_in[1];
    const float* c1w  = (const float*)d_in[2];
    const float* bn1g = (const float*)d_in[3];
    const float* bn1b = (const float*)d_in[4];
    const float* c2w  = (const float*)d_in[5];
    const float* bn2g = (const float*)d_in[6];
    const float* bn2b = (const float*)d_in[7];
    const float* vw   = (const float*)d_in[8];
    const float* vb   = (const float*)d_in[9];
    const float* aw   = (const float*)d_in[10];
    const float* abv  = (const float*)d_in[11];
    const float* pw   = (const float*)d_in[12];
    const float* pb   = (const float*)d_in[13];
    const float* c3w  = (const float*)d_in[14];
    const float* bn3g = (const float*)d_in[15];
    const float* bn3b = (const float*)d_in[16];
    const float* c4w  = (const float*)d_in[17];
    const float* bn4g = (const float*)d_in[18];
    const float* bn4b = (const float*)d_in[19];

    char* wsp = (char*)d_ws;
    size_t off = 0;
    auto carve = [&](size_t bytes) {
        void* pp = wsp + off;
        off += (bytes + 255) & ~(size_t)255;
        return pp;
    };
    u16*   xb   = (u16*)carve((size_t)8 * LPIX * 64 * 2);     // x NHWC bf16
    u16*   fgb  = (u16*)carve((size_t)8 * LPIX * 128 * 2);    // fg NHWC bf16
    u16*   actA = (u16*)carve((size_t)8 * LPIX * 128 * 2);
    u16*   actB = (u16*)carve((size_t)8 * LPIX * 128 * 2);
    u16*   Abuf = (u16*)carve((size_t)8 * 324 * LPIX * 2);    // A bf16
    u16*   w1p  = (u16*)carve((size_t)9 * 2 * 128 * 32 * 2);
    u16*   w2p  = (u16*)carve((size_t)9 * 4 * 128 * 32 * 2);
    u16*   w3p  = (u16*)carve((size_t)9 * 4 * 128 * 32 * 2);
    u16*   w4p  = (u16*)carve((size_t)9 * 4 * 128 * 32 * 2);
    u16*   vwp  = (u16*)carve((size_t)128 * 128 * 2);
    u16*   pwp  = (u16*)carve((size_t)128 * 128 * 2);
    u16*   awp  = (u16*)carve((size_t)4 * 1536 * 8 * 2);      // pre-swizzled attn W

    // --- pre-casts ---
    cast_nchw_nhwc<64><<<dim3(HW, 8), 256, 0, stream>>>(x, xb);
    cast_nchw_nhwc<128><<<dim3(HW, 8), 256, 0, stream>>>(fg, fgb);
    cast_conv_w<<<(9 * 64 * 128 + 255) / 256, 256, 0, stream>>>(c1w, w1p, 64);
    cast_conv_w<<<(9 * 128 * 128 + 255) / 256, 256, 0, stream>>>(c2w, w2p, 128);
    cast_conv_w<<<(9 * 128 * 128 + 255) / 256, 256, 0, stream>>>(c3w, w3p, 128);
    cast_conv_w<<<(9 * 128 * 128 + 255) / 256, 256, 0, stream>>>(c4w, w4p, 128);
    cast_mat<<<(16384 + 255) / 256, 256, 0, stream>>>(vw, vwp, 16384);
    cast_mat<<<(16384 + 255) / 256, 256, 0, stream>>>(pw, pwp, 16384);
    cast_attn_w<<<192, 256, 0, stream>>>(aw, awp);

    // --- pipeline ---
    conv_gemm<64, false><<<dim3(32, 8), 768, 0, stream>>>(xb, w1p, bn1g, bn1b, actA);
    conv_gemm<128, false><<<dim3(32, 8), 768, 0, stream>>>(actA, w2p, bn2g, bn2b, actB);
    linear_mfma<<<1152, 256, 0, stream>>>(actB, vwp, vb, actA);                 // v
    attn_mfma<<<dim3(72, 4, 8), 256, 0, stream>>>(fgb, awp, abv, Abuf);
    attn_fold<<<dim3(24, 4, 8), 384, 0, stream>>>(Abuf, actA, actB);            // folded
    linear_mfma<<<1152, 256, 0, stream>>>(actB, pwp, pb, actA);                 // p
    conv_gemm<128, false><<<dim3(32, 8), 768, 0, stream>>>(actA, w3p, bn3g, bn3b, actB);
    conv_gemm<128, true><<<dim3(32, 8), 768, 0, stream>>>(actB, w4p, bn4g, bn4b, d_out);
}

// Round 8
// 350.888 us; speedup vs baseline: 1.3576x; 1.0405x over previous
//
#include <hip/hip_runtime.h>
#include <math.h>

typedef __attribute__((ext_vector_type(8))) short short8;
typedef __attribute__((ext_vector_type(4))) float f32x4;
typedef unsigned short u16;
typedef unsigned int u32;

#define HW   96
#define LPIX 9216
static constexpr float kScale = 0.17677669529663687f;  // 1/sqrt(32)

__device__ inline u16 f2bf(float f) {
    u32 x = __float_as_uint(f);
    return (u16)((x + 0x7fffu + ((x >> 16) & 1u)) >> 16);   // RNE
}
__device__ inline float bf2f(u16 v) { return __uint_as_float((u32)v << 16); }

// global -> LDS direct copy, 16B per lane. LDS dest is wave-uniform base +
// lane*16 (HW semantics); global src is per-lane.
typedef __attribute__((address_space(1))) const void gas_t;
typedef __attribute__((address_space(3))) void las_t;
__device__ __forceinline__ void g2lds16(const void* g, void* l) {
    __builtin_amdgcn_global_load_lds((gas_t*)g, (las_t*)l, 16, 0, 0);
}

// counted vmcnt wait (loads stay in flight) + scheduling fence (rule #18)
#define WAITV(n) do {                                                   \
        asm volatile("s_waitcnt vmcnt(" #n ")" ::: "memory");           \
        __builtin_amdgcn_sched_barrier(0);                              \
    } while (0)
#define SFENCE() __builtin_amdgcn_sched_barrier(0)

// ---------------------------------------------------------------------------
// Fused NCHW fp32 -> NHWC bf16 transpose-cast for x (C=64) and fg (C=128).
// grid (96 y, 8 b, 2 src), block 256.
// ---------------------------------------------------------------------------
__global__ __launch_bounds__(256) void cast_nchw_nhwc_all(
    const float* __restrict__ x, const float* __restrict__ fg,
    u16* __restrict__ xb, u16* __restrict__ fgb)
{
    const int y = blockIdx.x, b = blockIdx.y, tid = threadIdx.x;
    const int isfg = blockIdx.z;
    const float* in = isfg ? fg : x;
    u16* out = isfg ? fgb : xb;
    const int C = isfg ? 128 : 64;

    __shared__ float sT[HW * 128];
    for (int i = tid; i < HW * C; i += 256) {
        int c = i / HW, xx = i - c * HW;
        sT[xx * C + c] = in[(((size_t)b * C + c) * HW + y) * HW + xx];
    }
    __syncthreads();
    for (int i = tid; i < HW * (C / 8); i += 256) {
        int c8 = i % (C / 8), xx = i / (C / 8);
        union { short8 v8; u16 u[8]; } pk;
#pragma unroll
        for (int j = 0; j < 8; ++j) pk.u[j] = f2bf(sT[xx * C + c8 * 8 + j]);
        *(short8*)&out[(((size_t)b * HW + y) * HW + xx) * C + c8 * 8] = pk.v8;
    }
}

// ---------------------------------------------------------------------------
// conv weight transform: [co 128][ci CIN][3][3] fp32 -> granule layout
//   [c NC][f 9][ch 2][m 64][s 4][e 8], ci = c*32 + ((s-(m>>1))&3)*8 + e.
// ---------------------------------------------------------------------------
__device__ __forceinline__ void conv_w_elem(
    const float* __restrict__ w, u16* __restrict__ wp, int CIN, int i)
{
    int e  = i & 7;
    int gr = i >> 3;                 // granule index
    int c  = gr / 4608;              // 32-ci chunk
    int gi = gr - c * 4608;
    int f  = gi >> 9;
    int rr = gi & 511;
    int ch = rr >> 8;
    int m  = (rr >> 2) & 63;
    int s  = rr & 3;
    int qq = (s - (m >> 1)) & 3;
    int co = ch * 64 + m;
    int ci = c * 32 + qq * 8 + e;
    wp[i] = f2bf(w[(size_t)(co * CIN + ci) * 9 + f]);
}

// attn weight transform: [324][128] fp32 -> wp[h][c4 4][rr 96][s 4][e 8],
// ci = c4*32 + ((s-(rr>>1))&3)*8 + e, rows 81..95 zero-padded.
__device__ __forceinline__ void attn_w_elem(
    const float* __restrict__ aw, u16* __restrict__ wp, int i)
{
    int e = i & 7;
    int g = i >> 3;
    int h = g / 1536, r = g - h * 1536;
    int c4 = r / 384, r2 = r - c4 * 384;
    int rr = r2 >> 2, s = r2 & 3;
    int qq = (s - (rr >> 1)) & 3;
    int ci = c4 * 32 + qq * 8 + e;
    float v = (rr < 81) ? aw[(size_t)(h * 81 + rr) * 128 + ci] : 0.f;
    wp[i] = f2bf(v);
}

// ---------------------------------------------------------------------------
// ALL weight pre-casts fused into one dispatch. Index-range demux:
//   [0,73728)      c1w -> w1p  (CIN=64)
//   [..,+147456)   c2w -> w2p  (CIN=128)
//   [..,+147456)   c3w -> w3p
//   [..,+147456)   c4w -> w4p
//   [..,+16384)    vw  -> vwp  (plain cast)
//   [..,+16384)    pw  -> pwp
//   [..,+49152)    aw  -> awp  (attn transform)
// total 598016 = 2336 blocks x 256.
// ---------------------------------------------------------------------------
__global__ __launch_bounds__(256) void cast_weights_all(
    const float* __restrict__ c1w, const float* __restrict__ c2w,
    const float* __restrict__ c3w, const float* __restrict__ c4w,
    const float* __restrict__ vw,  const float* __restrict__ pw,
    const float* __restrict__ aw,
    u16* __restrict__ w1p, u16* __restrict__ w2p,
    u16* __restrict__ w3p, u16* __restrict__ w4p,
    u16* __restrict__ vwp, u16* __restrict__ pwp, u16* __restrict__ awp)
{
    int i = blockIdx.x * 256 + threadIdx.x;
    if (i < 73728)  { conv_w_elem(c1w, w1p, 64, i);  return; }
    i -= 73728;
    if (i < 147456) { conv_w_elem(c2w, w2p, 128, i); return; }
    i -= 147456;
    if (i < 147456) { conv_w_elem(c3w, w3p, 128, i); return; }
    i -= 147456;
    if (i < 147456) { conv_w_elem(c4w, w4p, 128, i); return; }
    i -= 147456;
    if (i < 16384)  { vwp[i] = f2bf(vw[i]); return; }
    i -= 16384;
    if (i < 16384)  { pwp[i] = f2bf(pw[i]); return; }
    i -= 16384;
    attn_w_elem(aw, awp, i);             // i in [0, 49152)
}

// ---------------------------------------------------------------------------
// conv3x3 + BN + ReLU, v5: 12-wave pipelined blocks (3 waves/SIMD).
// (unchanged from R7 — verified)
// ---------------------------------------------------------------------------
template <int CIN, bool OUT_F32>
__global__ __launch_bounds__(768, 1) void conv_gemm(
    const u16* __restrict__ in, const u16* __restrict__ wp,
    const float* __restrict__ g, const float* __restrict__ be, void* outv)
{
    constexpr int NC   = CIN / 32;       // 32-ci chunks (2 or 4)
    constexpr int WBYT = 73728;          // weights: 4608 granules x 16B
    constexpr int HBYT = 36864;          // halo buf: 576 rows x 64B (2304 gran)

    const int bx = blockIdx.x;           // 0..31
    const int b  = blockIdx.y;
    const int y0 = bx * 3;               // rows y0..y0+2
    const int l0 = y0 * 96;

    const int tid = threadIdx.x, lane = tid & 63, wv = tid >> 6;  // wv 0..11
    const int half = wv & 1, ch = (wv >> 1) & 1, r = wv >> 2;
    const int lx = lane & 15, q = lane >> 4;

    __shared__ __align__(16) char smem[WBYT + 2 * HBYT];   // 147,456 B
    float* sT = (float*)smem;            // epilogue bf16 path [144][130]
    float* sF = (float*)smem;            // epilogue f32 path [128][148]

    const int aoff = lx * 64 + (((q + (lx >> 1)) & 3) << 4);
    const int pb   = r * 96 + half * 48 + lx;

    f32x4 acc[4][3];
#pragma unroll
    for (int mt = 0; mt < 4; ++mt)
#pragma unroll
        for (int nt = 0; nt < 3; ++nt) acc[mt][nt] = (f32x4){0.f, 0.f, 0.f, 0.f};

    const u16* inb = in + (size_t)b * LPIX * CIN;

    auto STAGE_W = [&](int c) {          // 6 uniform issues/thread
#pragma unroll
        for (int j = 0; j < 6; ++j) {
            g2lds16(&wp[((size_t)c * 4608 + j * 768 + tid) * 8],
                    (char*)smem + (j * 768 + wv * 64) * 16);
        }
    };
    auto STAGE_H = [&](int c, int buf) { // 3 uniform issues/thread (2304 gran)
#pragma unroll
        for (int i = 0; i < 3; ++i) {
            int gi = i * 768 + tid;      // 0..2303
            int p  = gi >> 2, s = gi & 3;
            int qq = (s - (p >> 1)) & 3;
            int lh = l0 - 96 + p;        // rows l0-96 .. l0+479 (clamped)
            lh = lh < 0 ? 0 : (lh >= LPIX ? LPIX - 1 : lh);
            g2lds16(&inb[(size_t)lh * CIN + c * 32 + qq * 8],
                    (char*)smem + WBYT + buf * HBYT + (i * 768 + wv * 64) * 16);
        }
    };
    auto TAP = [&](int f, int hbuf) {
        const int dy = f / 3 - 1, dx = f % 3 - 1;
        const int off = dy * 96 + dx + 96;           // pm = pb + nt*16 + off
        const bool vy = (unsigned)(y0 + r + dy) < 96u;
        const char* hb = (const char*)smem + WBYT + hbuf * HBYT;
        short8 af[4], bfr[3];
#pragma unroll
        for (int mt = 0; mt < 4; ++mt)
            af[mt] = *(const short8*)((const char*)smem + (f * 2 + ch) * 4096
                                      + mt * 1024 + aoff);
#pragma unroll
        for (int nt = 0; nt < 3; ++nt) {
            int pm = pb + nt * 16 + off;             // staged-row idx (-1..479)
            int slot = (q + (pm >> 1)) & 3;
            short8 t8 = *(const short8*)(hb + pm * 64 + slot * 16);
            bool ok = vy & ((unsigned)(half * 48 + nt * 16 + lx + dx) < 96u);
            bfr[nt] = ok ? t8 : (short8){0, 0, 0, 0, 0, 0, 0, 0};
        }
#pragma unroll
        for (int mt = 0; mt < 4; ++mt)
#pragma unroll
            for (int nt = 0; nt < 3; ++nt)
                acc[mt][nt] = __builtin_amdgcn_mfma_f32_16x16x32_bf16(
                    af[mt], bfr[nt], acc[mt][nt], 0, 0, 0);
    };

    // ---- prologue: stage chunk 0 (halo+weights) and chunk 1 halo ----
    STAGE_H(0, 0);
    SFENCE();
    STAGE_W(0);
    SFENCE();
    STAGE_H(1, 1);                       // NC >= 2 always
    SFENCE();
    WAITV(3);                            // h0+w0 landed; h1 flies
    __builtin_amdgcn_s_barrier();
    asm volatile("" ::: "memory");

#pragma unroll
    for (int c = 0; c < NC; ++c) {
        const int hbuf = c & 1;
        TAP(0, hbuf); TAP(1, hbuf); TAP(2, hbuf);
        TAP(3, hbuf); TAP(4, hbuf); TAP(5, hbuf);
        TAP(6, hbuf); TAP(7, hbuf); TAP(8, hbuf);
        if (c + 1 < NC) {
            // all waves done reading weights_c and halo buf (c&1)
            asm volatile("s_waitcnt lgkmcnt(0)" ::: "memory");
            __builtin_amdgcn_s_barrier();
            asm volatile("" ::: "memory");
            STAGE_W(c + 1);                          // overwrite weight region
            SFENCE();
            if (c + 2 < NC) STAGE_H(c + 2, c & 1);   // overwrite halo buf c&1
            SFENCE();
            // outstanding: h_{c+1}(3, landed) + w_{c+1}(6) [+ h_{c+2}(3)]
            if (c + 2 < NC) { WAITV(3); } else { WAITV(0); }
            __builtin_amdgcn_s_barrier();
            asm volatile("" ::: "memory");
        }
    }

    // ---- epilogue ----
    asm volatile("s_waitcnt lgkmcnt(0) vmcnt(0)" ::: "memory");
    __builtin_amdgcn_s_barrier();
    asm volatile("" ::: "memory");

    const float rs = rsqrtf(1.f + 1e-5f);
    if (OUT_F32) {
        float* out = (float*)outv;
#pragma unroll
        for (int hh = 0; hh < 2; ++hh) {               // two 48-px halves
            if (hh) { __syncthreads(); }
            if (half == hh) {
#pragma unroll
                for (int mt = 0; mt < 4; ++mt)
#pragma unroll
                    for (int nt = 0; nt < 3; ++nt)
#pragma unroll
                        for (int reg = 0; reg < 4; ++reg)
                            sF[(ch * 64 + mt * 16 + q * 4 + reg) * 148
                               + r * 48 + nt * 16 + lx] = acc[mt][nt][reg];
            }
            __syncthreads();
            for (int i = tid; i < 4608; i += 768) {
                int co = i / 36, r2 = i - co * 36;
                int wrr = r2 / 12, j = r2 - wrr * 12;
                float sc = g[co] * rs, bb = be[co];
                f32x4 vv = *(const f32x4*)&sF[co * 148 + wrr * 48 + j * 4];
#pragma unroll
                for (int e = 0; e < 4; ++e) vv[e] = fmaxf(fmaf(vv[e], sc, bb), 0.f);
                *(f32x4*)&out[((size_t)b * 128 + co) * LPIX
                              + (y0 + wrr) * 96 + hh * 48 + j * 4] = vv;
            }
            if (!hh) __syncthreads();
        }
    } else {
        u16* out = (u16*)outv;
#pragma unroll
        for (int hh = 0; hh < 2; ++hh) {               // two 48-px halves
            if (hh) { __syncthreads(); }
            if (half == hh) {
#pragma unroll
                for (int mt = 0; mt < 4; ++mt)
#pragma unroll
                    for (int nt = 0; nt < 3; ++nt)
#pragma unroll
                        for (int reg = 0; reg < 4; ++reg)
                            sT[(r * 48 + nt * 16 + lx) * 130
                               + ch * 64 + mt * 16 + q * 4 + reg] = acc[mt][nt][reg];
            }
            __syncthreads();
            for (int i = tid; i < 2304; i += 768) {
                int cog = i & 15, pxl = i >> 4;        // 16 co-groups x 144 px
                int wrr = pxl / 48, ofs = pxl - wrr * 48;
                int l = (y0 + wrr) * 96 + hh * 48 + ofs;
                union { short8 v8; u16 u[8]; } pk;
#pragma unroll
                for (int j = 0; j < 8; ++j) {
                    int co = cog * 8 + j;
                    pk.u[j] = f2bf(fmaxf(fmaf(sT[pxl * 130 + cog * 8 + j],
                                              g[co] * rs, be[co]), 0.f));
                }
                *(short8*)&out[((size_t)b * LPIX + l) * 128 + cog * 8] = pk.v8;
            }
            if (!hh) __syncthreads();
        }
    }
}

// ---------------------------------------------------------------------------
// 128->128 linear + bias via MFMA. in/out NHWC-flat bf16 [b*L][128].
// grid 1152 (64 px per block), block 256 (2x2 waves: M=64 x N=32).
// ---------------------------------------------------------------------------
__global__ __launch_bounds__(256) void linear_mfma(
    const u16* __restrict__ in, const u16* __restrict__ wp,
    const float* __restrict__ bias, u16* __restrict__ out)
{
    const int l0 = blockIdx.x * 64;
    const int tid = threadIdx.x, lane = tid & 63, wv = tid >> 6;
    const int wm = wv >> 1, wn = wv & 1;
    const int lx = lane & 15, q = lane >> 4;

    __shared__ char smem[4 * 64 * 40 * 2 + 4 * 128 * 40 * 2];   // 61,440 B
    u16* sX = (u16*)smem;                        // [c4][px 64][32 pitch 40]
    u16* sW = (u16*)(smem + 4 * 64 * 40 * 2);    // [c4][co 128][32 pitch 40]
    float* sT = (float*)smem;                    // epilogue [64][65]

    for (int i = tid; i < 1024; i += 256) {
        int k8 = i & 15, px = i >> 4;
        short8 v = *(const short8*)&in[((size_t)(l0 + px)) * 128 + k8 * 8];
        *(short8*)&sX[((k8 >> 2) * 64 + px) * 40 + (k8 & 3) * 8] = v;
    }
    for (int i = tid; i < 2048; i += 256) {
        int k8 = i & 15, co = i >> 4;
        short8 v = *(const short8*)&wp[(size_t)co * 128 + k8 * 8];
        *(short8*)&sW[((k8 >> 2) * 128 + co) * 40 + (k8 & 3) * 8] = v;
    }
    __syncthreads();

    f32x4 acc[4][2];
#pragma unroll
    for (int mt = 0; mt < 4; ++mt)
#pragma unroll
        for (int nt = 0; nt < 2; ++nt) acc[mt][nt] = (f32x4){0.f, 0.f, 0.f, 0.f};

#pragma unroll
    for (int c4 = 0; c4 < 4; ++c4) {
        short8 af[4], bfr[2];
#pragma unroll
        for (int mt = 0; mt < 4; ++mt)
            af[mt] = *(const short8*)&sW[(c4 * 128 + wm * 64 + mt * 16 + lx) * 40 + q * 8];
#pragma unroll
        for (int nt = 0; nt < 2; ++nt)
            bfr[nt] = *(const short8*)&sX[(c4 * 64 + wn * 32 + nt * 16 + lx) * 40 + q * 8];
#pragma unroll
        for (int mt = 0; mt < 4; ++mt)
#pragma unroll
            for (int nt = 0; nt < 2; ++nt)
                acc[mt][nt] = __builtin_amdgcn_mfma_f32_16x16x32_bf16(
                    af[mt], bfr[nt], acc[mt][nt], 0, 0, 0);
    }

    for (int mh = 0; mh < 2; ++mh) {
        __syncthreads();
        if (wm == mh) {
#pragma unroll
            for (int mt = 0; mt < 4; ++mt)
#pragma unroll
                for (int nt = 0; nt < 2; ++nt)
#pragma unroll
                    for (int reg = 0; reg < 4; ++reg)
                        sT[(wn * 32 + nt * 16 + lx) * 65 + mt * 16 + q * 4 + reg] =
                            acc[mt][nt][reg];
        }
        __syncthreads();
        for (int i = tid; i < 512; i += 256) {
            int cog = i & 7, px = i >> 3;
            union { short8 v8; u16 u[8]; } pk;
#pragma unroll
            for (int j = 0; j < 8; ++j) {
                int co = mh * 64 + cog * 8 + j;
                pk.u[j] = f2bf(sT[px * 65 + cog * 8 + j] + bias[co]);
            }
            *(short8*)&out[((size_t)(l0 + px)) * 128 + mh * 64 + cog * 8] = pk.v8;
        }
    }
}

// ---------------------------------------------------------------------------
// attn logits GEMM (MFMA) + bias + scale + softmax over q(9), v2 (see R3).
// ---------------------------------------------------------------------------
__global__ __launch_bounds__(256, 2) void attn_mfma(
    const u16* __restrict__ fgb, const u16* __restrict__ awp,
    const float* __restrict__ ab, u16* __restrict__ A)
{
    const int lt = blockIdx.x, h = blockIdx.y, b = blockIdx.z;
    const int l0 = lt * 128;
    const int tid = threadIdx.x, lane = tid & 63, wv = tid >> 6;
    const int lx = lane & 15, q = lane >> 4;

    __shared__ __align__(16) char smem[57344];
    float* sL = (float*)smem;            // epilogue logits [128][97] (49,664 B)

    // ---- stage sX: [c4 4][px 128][4 slots][16B] = 2048 granules ----
    const u16* fb = fgb + ((size_t)b * LPIX + l0) * 128;
#pragma unroll
    for (int i = 0; i < 8; ++i) {
        int gg = i * 256 + tid;
        int c4 = gg >> 9, r = gg & 511, px = r >> 2, s = r & 3;
        int qq = (s - (px >> 1)) & 3;
        g2lds16(&fb[(size_t)px * 128 + c4 * 32 + qq * 8],
                (char*)smem + (i * 256 + wv * 64) * 16);
    }
    // ---- stage sW: 1536 granules, pre-swizzled linear source ----
    const u16* wb = awp + (size_t)h * 1536 * 8;
#pragma unroll
    for (int i = 0; i < 6; ++i) {
        g2lds16(&wb[(size_t)(i * 256 + tid) * 8],
                (char*)smem + 32768 + (i * 256 + wv * 64) * 16);
    }
    asm volatile("s_waitcnt vmcnt(0)" ::: "memory");
    __builtin_amdgcn_s_barrier();
    asm volatile("" ::: "memory");

    f32x4 acc[2][6];
#pragma unroll
    for (int nt = 0; nt < 2; ++nt)
#pragma unroll
        for (int j = 0; j < 6; ++j) acc[nt][j] = (f32x4){0.f, 0.f, 0.f, 0.f};

#pragma unroll
    for (int c4 = 0; c4 < 4; ++c4) {
        short8 af[2], bfr[6];
#pragma unroll
        for (int nt = 0; nt < 2; ++nt) {
            int px = wv * 32 + nt * 16 + lx;
            af[nt] = *(const short8*)((const char*)smem + c4 * 8192 + px * 64
                                      + (((q + (px >> 1)) & 3) << 4));
        }
#pragma unroll
        for (int j = 0; j < 6; ++j) {
            int rr = j * 16 + lx;
            bfr[j] = *(const short8*)((const char*)smem + 32768 + c4 * 6144 + rr * 64
                                      + (((q + (rr >> 1)) & 3) << 4));
        }
#pragma unroll
        for (int nt = 0; nt < 2; ++nt)
#pragma unroll
            for (int j = 0; j < 6; ++j)
                acc[nt][j] = __builtin_amdgcn_mfma_f32_16x16x32_bf16(
                    af[nt], bfr[j], acc[nt][j], 0, 0, 0);
    }

    __syncthreads();   // done reading sX/sW; reuse as sL
#pragma unroll
    for (int nt = 0; nt < 2; ++nt)
#pragma unroll
        for (int j = 0; j < 6; ++j)
#pragma unroll
            for (int reg = 0; reg < 4; ++reg)
                sL[(wv * 32 + nt * 16 + q * 4 + reg) * 97 + j * 16 + lx] =
                    acc[nt][j][reg];
    __syncthreads();

    for (int t = tid; t < 1152; t += 256) {
        int px = t & 127, p = t >> 7;
        const int rbase = h * 81 + p * 9;
        float lg[9], m = -1e30f;
#pragma unroll
        for (int qq = 0; qq < 9; ++qq) {
            lg[qq] = (sL[px * 97 + p * 9 + qq] + ab[rbase + qq]) * kScale;
            m = fmaxf(m, lg[qq]);
        }
        float s = 0.f;
#pragma unroll
        for (int qq = 0; qq < 9; ++qq) { lg[qq] = __expf(lg[qq] - m); s += lg[qq]; }
        float inv = 1.f / s;
        u16* Ab = &A[(((size_t)(b * 4 + h) * 9 + p) * 9) * LPIX + l0 + px];
#pragma unroll
        for (int qq = 0; qq < 9; ++qq) Ab[(size_t)qq * LPIX] = f2bf(lg[qq] * inv);
    }
}

// ---------------------------------------------------------------------------
// fused einsum + fold (5x5 stencil collapse). (unchanged)
// ---------------------------------------------------------------------------
__global__ __launch_bounds__(384, 4) void attn_fold(
    const u16* __restrict__ A, const u16* __restrict__ v,
    u16* __restrict__ out)
{
    const int yt = blockIdx.x, h = blockIdx.y, b = blockIdx.z;
    const int y0 = yt * 4;
    const int tid = threadIdx.x;          // 0..383
    const int yl  = tid / 96;             // 0..3
    const int x   = tid - yl * 96;
    const int y   = y0 + yl;
    const int l   = y * 96 + x;

    __shared__ u16 sV[8 * 96 * 32];       // [r 8][xx 96][c 32] bf16 = 49,152 B

    // ---- stage v rows y0-2 .. y0+5 (this head's 32 ch) ----
    const u16* vb = v + (size_t)b * LPIX * 128 + h * 32;
    for (int t = tid; t < 3072; t += 384) {
        int k = t & 3, s = t >> 2;        // s = r*96+xx, k = uint4 within 64B
        int r = s / 96, xx = s - r * 96;
        int gy = y0 - 2 + r;
        uint4 uu = make_uint4(0u, 0u, 0u, 0u);
        if ((unsigned)gy < 96u)
            uu = *(const uint4*)&vb[(size_t)(gy * 96 + xx) * 128 + k * 8];
        *(uint4*)&sV[(size_t)s * 32 + k * 8] = uu;
    }

    // ---- stencil S[5][5] from 9 taps x 9 q of A (coalesced bf16 reads) ----
    float S[25];
#pragma unroll
    for (int i = 0; i < 25; ++i) S[i] = 0.f;

    const u16* Ab = A + ((size_t)(b * 4 + h) * 81) * (size_t)LPIX;
#pragma unroll
    for (int ki = 0; ki < 3; ++ki) {
        const int ly = y + 1 - ki;
        const bool vy = ((unsigned)ly < 96u);
#pragma unroll
        for (int kj = 0; kj < 3; ++kj) {
            const int lx2 = x + 1 - kj;
            if (vy && (unsigned)lx2 < 96u) {
                const u16* Ap = Ab + (size_t)(ki * 3 + kj) * 9 * (size_t)LPIX
                              + (ly * 96 + lx2);
#pragma unroll
                for (int qq = 0; qq < 9; ++qq) {
                    const int qi = qq / 3, qj = qq - qi * 3;
                    S[(qi - ki + 2) * 5 + (qj - kj + 2)] += bf2f(Ap[(size_t)qq * LPIX]);
                }
            }
        }
    }

    __syncthreads();   // staging complete before LDS reads

    // ---- 5x5 stencil over LDS v tile ----
    float acc[32];
#pragma unroll
    for (int c = 0; c < 32; ++c) acc[c] = 0.f;

#pragma unroll
    for (int oy = 0; oy < 5; ++oy) {
        const int r = yl + oy;            // LDS row: gy = y0-2+r = y+oy-2
#pragma unroll
        for (int ox = 0; ox < 5; ++ox) {
            const int xx = x + ox - 2;
            if ((unsigned)xx >= 96u) continue;
            const float sc = S[oy * 5 + ox];
            const u16* vp = &sV[(size_t)(r * 96 + xx) * 32];
#pragma unroll
            for (int c8 = 0; c8 < 4; ++c8) {
                const uint4 uu = *(const uint4*)&vp[c8 * 8];
                acc[c8 * 8 + 0] = fmaf(sc, __uint_as_float(uu.x << 16),          acc[c8 * 8 + 0]);
                acc[c8 * 8 + 1] = fmaf(sc, __uint_as_float(uu.x & 0xffff0000u), acc[c8 * 8 + 1]);
                acc[c8 * 8 + 2] = fmaf(sc, __uint_as_float(uu.y << 16),          acc[c8 * 8 + 2]);
                acc[c8 * 8 + 3] = fmaf(sc, __uint_as_float(uu.y & 0xffff0000u), acc[c8 * 8 + 3]);
                acc[c8 * 8 + 4] = fmaf(sc, __uint_as_float(uu.z << 16),          acc[c8 * 8 + 4]);
                acc[c8 * 8 + 5] = fmaf(sc, __uint_as_float(uu.z & 0xffff0000u), acc[c8 * 8 + 5]);
                acc[c8 * 8 + 6] = fmaf(sc, __uint_as_float(uu.w << 16),          acc[c8 * 8 + 6]);
                acc[c8 * 8 + 7] = fmaf(sc, __uint_as_float(uu.w & 0xffff0000u), acc[c8 * 8 + 7]);
            }
        }
    }

    u16* ob = &out[((size_t)b * LPIX + l) * 128 + h * 32];
#pragma unroll
    for (int gidx = 0; gidx < 4; ++gidx) {
        union { short8 v8; u16 u[8]; } pk;
#pragma unroll
        for (int j = 0; j < 8; ++j) pk.u[j] = f2bf(acc[gidx * 8 + j]);
        *(short8*)&ob[gidx * 8] = pk.v8;
    }
}

// ---------------------------------------------------------------------------
extern "C" void kernel_launch(void* const* d_in, const int* in_sizes, int n_in,
                              void* d_out, int out_size, void* d_ws, size_t ws_size,
                              hipStream_t stream)
{
    const float* x    = (const float*)d_in[0];
    const float* fg   = (const float*)d_in[1];
    const float* c1w  = (const float*)d_in[2];
    const float* bn1g = (const float*)d_in[3];
    const float* bn1b = (const float*)d_in[4];
    const float* c2w  = (const float*)d_in[5];
    const float* bn2g = (const float*)d_in[6];
    const float* bn2b = (const float*)d_in[7];
    const float* vw   = (const float*)d_in[8];
    const float* vb   = (const float*)d_in[9];
    const float* aw   = (const float*)d_in[10];
    const float* abv  = (const float*)d_in[11];
    const float* pw   = (const float*)d_in[12];
    const float* pb   = (const float*)d_in[13];
    const float* c3w  = (const float*)d_in[14];
    const float* bn3g = (const float*)d_in[15];
    const float* bn3b = (const float*)d_in[16];
    const float* c4w  = (const float*)d_in[17];
    const float* bn4g = (const float*)d_in[18];
    const float* bn4b = (const float*)d_in[19];

    char* wsp = (char*)d_ws;
    size_t off = 0;
    auto carve = [&](size_t bytes) {
        void* pp = wsp + off;
        off += (bytes + 255) & ~(size_t)255;
        return pp;
    };
    u16*   xb   = (u16*)carve((size_t)8 * LPIX * 64 * 2);     // x NHWC bf16
    u16*   fgb  = (u16*)carve((size_t)8 * LPIX * 128 * 2);    // fg NHWC bf16
    u16*   actA = (u16*)carve((size_t)8 * LPIX * 128 * 2);
    u16*   actB = (u16*)carve((size_t)8 * LPIX * 128 * 2);
    u16*   Abuf = (u16*)carve((size_t)8 * 324 * LPIX * 2);    // A bf16
    u16*   w1p  = (u16*)carve((size_t)9 * 2 * 128 * 32 * 2);
    u16*   w2p  = (u16*)carve((size_t)9 * 4 * 128 * 32 * 2);
    u16*   w3p  = (u16*)carve((size_t)9 * 4 * 128 * 32 * 2);
    u16*   w4p  = (u16*)carve((size_t)9 * 4 * 128 * 32 * 2);
    u16*   vwp  = (u16*)carve((size_t)128 * 128 * 2);
    u16*   pwp  = (u16*)carve((size_t)128 * 128 * 2);
    u16*   awp  = (u16*)carve((size_t)4 * 1536 * 8 * 2);      // pre-swizzled attn W

    // --- pre-casts (fused: 9 dispatches -> 2) ---
    cast_nchw_nhwc_all<<<dim3(HW, 8, 2), 256, 0, stream>>>(x, fg, xb, fgb);
    cast_weights_all<<<2336, 256, 0, stream>>>(c1w, c2w, c3w, c4w, vw, pw, aw,
                                               w1p, w2p, w3p, w4p, vwp, pwp, awp);

    // --- pipeline ---
    conv_gemm<64, false><<<dim3(32, 8), 768, 0, stream>>>(xb, w1p, bn1g, bn1b, actA);
    conv_gemm<128, false><<<dim3(32, 8), 768, 0, stream>>>(actA, w2p, bn2g, bn2b, actB);
    linear_mfma<<<1152, 256, 0, stream>>>(actB, vwp, vb, actA);                 // v
    attn_mfma<<<dim3(72, 4, 8), 256, 0, stream>>>(fgb, awp, abv, Abuf);
    attn_fold<<<dim3(24, 4, 8), 384, 0, stream>>>(Abuf, actA, actB);            // folded
    linear_mfma<<<1152, 256, 0, stream>>>(actB, pwp, pb, actA);                 // p
    conv_gemm<128, false><<<dim3(32, 8), 768, 0, stream>>>(actA, w3p, bn3g, bn3b, actB);
    conv_gemm<128, true><<<dim3(32, 8), 768, 0, stream>>>(actB, w4p, bn4g, bn4b, d_out);
}